// Round 2
// baseline (2772.454 us; speedup 1.0000x reference)
//
#include <hip/hip_runtime.h>
#include <math.h>

// ---------------- zero fill ----------------
__global__ void zero_i32_k(int* __restrict__ p, int n) {
    int i = blockIdx.x * 256 + threadIdx.x;
    if (i < n) p[i] = 0;
}

// ---------------- embed: u = relu(x@W1+b1), h = x@Ws+bs ----------------
__global__ __launch_bounds__(256) void embed_k(
    const float* __restrict__ x, const float* __restrict__ W1, const float* __restrict__ b1,
    const float* __restrict__ Ws, const float* __restrict__ bs,
    float* __restrict__ u, float* __restrict__ h, int Nn)
{
    int idx = blockIdx.x * 256 + threadIdx.x;
    if (idx >= Nn * 128) return;
    int n = idx >> 7, c = idx & 127;
    float x0 = x[2*n], x1 = x[2*n+1];
    float uu = fmaf(x1, W1[128+c], fmaf(x0, W1[c], b1[c]));
    u[idx] = fmaxf(uu, 0.0f);
    h[idx] = fmaf(x1, Ws[128+c], fmaf(x0, Ws[c], bs[c]));
}

// ------- generic fp32 GEMM: C (+)= A[N x K] @ W[K x 128-tile] (+bias)(relu) -------
// 128x128 tile, 256 threads, 8x8 register blocking, K staged in 32-chunks (32KB LDS)
template<int RELU, int BETA>
__global__ __launch_bounds__(256) void gemm_k(
    const float* __restrict__ A, const float* __restrict__ W,
    const float* __restrict__ bias, float* __restrict__ C,
    int Nrows, int K, int ldW, int ldC)
{
    __shared__ float As[32][128];   // [k][row]
    __shared__ float Wsh[32][128];  // [k][col]
    const int row0 = blockIdx.x * 128;
    const int col0 = blockIdx.y * 128;
    const int t  = threadIdx.x;
    const int tx = t & 15;   // col group (8 cols)
    const int ty = t >> 4;   // row group (8 rows)
    float acc[8][8];
    #pragma unroll
    for (int i = 0; i < 8; ++i)
        #pragma unroll
        for (int j = 0; j < 8; ++j) acc[i][j] = 0.f;

    for (int k0 = 0; k0 < K; k0 += 32) {
        #pragma unroll
        for (int it = 0; it < 4; ++it) {        // stage A: 128 rows x 32 k (transposed)
            int g = t + it * 256;
            int r = g >> 3;
            int kk = (g & 7) * 4;
            int gr = row0 + r;
            float4 v = make_float4(0.f, 0.f, 0.f, 0.f);
            if (gr < Nrows) v = *(const float4*)(A + (size_t)gr * K + k0 + kk);
            As[kk+0][r] = v.x; As[kk+1][r] = v.y; As[kk+2][r] = v.z; As[kk+3][r] = v.w;
        }
        #pragma unroll
        for (int it = 0; it < 4; ++it) {        // stage W: 32 k x 128 cols
            int g = t + it * 256;
            int kk = g >> 5;
            int cc = (g & 31) * 4;
            *(float4*)&Wsh[kk][cc] = *(const float4*)(W + (size_t)(k0 + kk) * ldW + col0 + cc);
        }
        __syncthreads();
        #pragma unroll
        for (int k = 0; k < 32; ++k) {
            float4 a0 = *(const float4*)&As[k][ty*8];
            float4 a1 = *(const float4*)&As[k][ty*8+4];
            float4 w0 = *(const float4*)&Wsh[k][tx*8];
            float4 w1 = *(const float4*)&Wsh[k][tx*8+4];
            float av[8] = {a0.x,a0.y,a0.z,a0.w,a1.x,a1.y,a1.z,a1.w};
            float wv[8] = {w0.x,w0.y,w0.z,w0.w,w1.x,w1.y,w1.z,w1.w};
            #pragma unroll
            for (int i = 0; i < 8; ++i)
                #pragma unroll
                for (int j = 0; j < 8; ++j)
                    acc[i][j] = fmaf(av[i], wv[j], acc[i][j]);
        }
        __syncthreads();
    }
    #pragma unroll
    for (int i = 0; i < 8; ++i) {
        int gr = row0 + ty*8 + i;
        if (gr >= Nrows) continue;
        size_t off = (size_t)gr * ldC + col0 + tx*8;
        #pragma unroll
        for (int jj = 0; jj < 2; ++jj) {
            float4 r;
            r.x = acc[i][jj*4+0]; r.y = acc[i][jj*4+1];
            r.z = acc[i][jj*4+2]; r.w = acc[i][jj*4+3];
            if (bias) {
                const float* bp = bias + col0 + tx*8 + jj*4;
                r.x += bp[0]; r.y += bp[1]; r.z += bp[2]; r.w += bp[3];
            }
            if (BETA) {
                float4 c0 = *(const float4*)(C + off + jj*4);
                r.x += c0.x; r.y += c0.y; r.z += c0.z; r.w += c0.w;
            }
            if (RELU) {
                r.x = fmaxf(r.x, 0.f); r.y = fmaxf(r.y, 0.f);
                r.z = fmaxf(r.z, 0.f); r.w = fmaxf(r.w, 0.f);
            }
            *(float4*)(C + off + jj*4) = r;
        }
    }
}

// ---------------- CSR build ----------------
__global__ void count_k(const int* __restrict__ dst, int* __restrict__ cnt, int E) {
    int e = blockIdx.x * 256 + threadIdx.x;
    if (e < E) atomicAdd(&cnt[dst[e]], 1);
}

__global__ __launch_bounds__(1024) void scan_k(const int* __restrict__ cnt,
    int* __restrict__ rowptr, int* __restrict__ wpos, int Nn)
{
    __shared__ int buf[1024];
    __shared__ int carry_s;
    if (threadIdx.x == 0) carry_s = 0;
    __syncthreads();
    for (int base = 0; base < Nn; base += 1024) {
        int i = base + (int)threadIdx.x;
        int v = (i < Nn) ? cnt[i] : 0;
        buf[threadIdx.x] = v;
        __syncthreads();
        for (int off = 1; off < 1024; off <<= 1) {
            int tv = (threadIdx.x >= (unsigned)off) ? buf[threadIdx.x - off] : 0;
            __syncthreads();
            buf[threadIdx.x] += tv;
            __syncthreads();
        }
        int incl = buf[threadIdx.x] + carry_s;
        if (i < Nn) { rowptr[i+1] = incl; wpos[i] = incl - v; }
        __syncthreads();
        if (threadIdx.x == 1023) carry_s = incl;
        __syncthreads();
    }
    if (threadIdx.x == 0) rowptr[0] = 0;
}

__global__ void scatter_k(const int* __restrict__ src, const int* __restrict__ dst,
                          int* __restrict__ wpos, int* __restrict__ esrc, int E) {
    int e = blockIdx.x * 256 + threadIdx.x;
    if (e < E) {
        int p = atomicAdd(&wpos[dst[e]], 1);
        esrc[p] = src[e];
    }
}

// ---------------- attention scalars el/er ----------------
__global__ __launch_bounds__(256) void elr_k(const float* __restrict__ z,
    const float* __restrict__ al, const float* __restrict__ ar,
    float* __restrict__ el, float* __restrict__ er, int Nn)
{
    int idx = blockIdx.x * 256 + threadIdx.x;  // n*16 + head
    if (idx >= Nn * 16) return;
    int hd = idx & 15;
    const float* zp = z + (size_t)idx * 8;     // n*128 + hd*8
    float4 z0 = *(const float4*)zp;
    float4 z1 = *(const float4*)(zp + 4);
    float4 a0 = *(const float4*)(al + hd*8);
    float4 a1 = *(const float4*)(al + hd*8 + 4);
    float4 r0 = *(const float4*)(ar + hd*8);
    float4 r1 = *(const float4*)(ar + hd*8 + 4);
    el[idx] = z0.x*a0.x + z0.y*a0.y + z0.z*a0.z + z0.w*a0.w
            + z1.x*a1.x + z1.y*a1.y + z1.z*a1.z + z1.w*a1.w;
    er[idx] = z0.x*r0.x + z0.y*r0.y + z0.z*r0.z + z0.w*r0.w
            + z1.x*r1.x + z1.y*r1.y + z1.z*r1.z + z1.w*r1.w;
}

// ---------------- GAT aggregate: one wave per node, t1 = h + attn + bias ----------------
__global__ __launch_bounds__(256) void gat_k(
    const float* __restrict__ h, const float* __restrict__ z,
    const float* __restrict__ el, const float* __restrict__ er,
    const int* __restrict__ rowptr, const int* __restrict__ esrc,
    const float* __restrict__ gbias, float* __restrict__ t1, int Nn)
{
    int gw = (blockIdx.x * 256 + threadIdx.x) >> 6;  // node = global wave id
    if (gw >= Nn) return;
    int lane = threadIdx.x & 63;
    int n = gw;
    int c = lane * 2;        // 2 channels per lane
    int head = lane >> 2;    // c/8
    float ern = er[n*16 + head];
    int beg = rowptr[n], end = rowptr[n+1];
    float m = -1e30f;
    for (int i = beg; i < end; ++i) {
        int s = esrc[i];
        float e = el[s*16 + head] + ern;
        e = (e > 0.f) ? e : 0.2f * e;
        m = fmaxf(m, e);
    }
    float den = 0.f, a0 = 0.f, a1 = 0.f;
    for (int i = beg; i < end; ++i) {
        int s = esrc[i];
        float e = el[s*16 + head] + ern;
        e = (e > 0.f) ? e : 0.2f * e;
        float w = __expf(e - m);
        float2 zz = *(const float2*)(z + (size_t)s*128 + c);
        den += w;
        a0 = fmaf(w, zz.x, a0);
        a1 = fmaf(w, zz.y, a1);
    }
    float inv = 1.f / den;   // den>0 guaranteed (every node has an incoming edge)
    size_t o = (size_t)n*128 + c;
    float2 hh = *(const float2*)(h + o);
    float2 r;
    r.x = hh.x + a0*inv + gbias[c];
    r.y = hh.y + a1*inv + gbias[c+1];
    *(float2*)(t1 + o) = r;
}

// ---------------- BatchNorm (training mode, biased var) ----------------
__global__ __launch_bounds__(256) void bn_stats_k(const float* __restrict__ xin,
    float* __restrict__ stats, int Nn)
{
    __shared__ float ss[256], sq[256];
    int c = threadIdx.x & 127;
    int half = threadIdx.x >> 7;
    float s = 0.f, q = 0.f;
    for (int r = blockIdx.x*2 + half; r < Nn; r += gridDim.x*2) {
        float v = xin[(size_t)r*128 + c];
        s += v; q = fmaf(v, v, q);
    }
    ss[threadIdx.x] = s; sq[threadIdx.x] = q;
    __syncthreads();
    if (half == 0) {
        atomicAdd(&stats[c],     ss[c] + ss[c+128]);
        atomicAdd(&stats[128+c], sq[c] + sq[c+128]);
    }
}

template<int WRITE2>
__global__ __launch_bounds__(256) void bn_apply_k(const float* __restrict__ xin,
    const float* __restrict__ stats, const float* __restrict__ g, const float* __restrict__ b,
    float* __restrict__ hout, float* __restrict__ t1out, int Nn)
{
    int idx = blockIdx.x * 256 + threadIdx.x;
    if (idx >= Nn * 128) return;
    int c = idx & 127;
    float invN = 1.f / (float)Nn;
    float mu = stats[c] * invN;
    float var = stats[128+c] * invN - mu*mu;
    float y = (xin[idx] - mu) * rsqrtf(var + 1e-5f) * g[c] + b[c];
    hout[idx] = y;
    if (WRITE2) t1out[idx] = y;   // residual base for FF accumulate
}

// ---------------- decoder output: out[n] = relu(dacc[n,:]) . W2 + b2 ----------------
__global__ __launch_bounds__(256) void dec_out_k(const float* __restrict__ dacc,
    const float* __restrict__ W2, const float* __restrict__ b2,
    float* __restrict__ out, int Nn)
{
    int gw = (blockIdx.x * 256 + threadIdx.x) >> 6;
    if (gw >= Nn) return;
    int lane = threadIdx.x & 63;
    const float* row = dacc + (size_t)gw * 128;
    float v0 = fmaxf(row[lane],      0.f);
    float v1 = fmaxf(row[64 + lane], 0.f);
    float p = v0 * W2[lane] + v1 * W2[64 + lane];
    #pragma unroll
    for (int off = 32; off > 0; off >>= 1) p += __shfl_down(p, off);
    if (lane == 0) out[gw] = p + b2[0];
}

extern "C" void kernel_launch(void* const* d_in, const int* in_sizes, int n_in,
                              void* d_out, int out_size, void* d_ws, size_t ws_size,
                              hipStream_t stream)
{
    const float* x      = (const float*)d_in[0];
    const int*   src    = (const int*)  d_in[1];
    const int*   dst    = (const int*)  d_in[2];
    const float* emb_W1 = (const float*)d_in[3];
    const float* emb_b1 = (const float*)d_in[4];
    const float* emb_W2 = (const float*)d_in[5];
    const float* emb_b2 = (const float*)d_in[6];
    const float* emb_Ws = (const float*)d_in[7];
    const float* emb_bs = (const float*)d_in[8];
    const float* gat_W  = (const float*)d_in[9];
    const float* gat_al = (const float*)d_in[10];
    const float* gat_ar = (const float*)d_in[11];
    const float* gat_b  = (const float*)d_in[12];
    const float* bn1_g  = (const float*)d_in[13];
    const float* bn1_b  = (const float*)d_in[14];
    const float* ff_W1  = (const float*)d_in[15];
    const float* ff_b1  = (const float*)d_in[16];
    const float* ff_W2  = (const float*)d_in[17];
    const float* ff_b2  = (const float*)d_in[18];
    const float* bn2_g  = (const float*)d_in[19];
    const float* bn2_b  = (const float*)d_in[20];
    const float* dec_W1 = (const float*)d_in[21];
    const float* dec_b1 = (const float*)d_in[22];
    const float* dec_W2 = (const float*)d_in[23];
    const float* dec_b2 = (const float*)d_in[24];
    float* out = (float*)d_out;
    (void)n_in; (void)out_size;

    const int N = in_sizes[0] / 2;
    const int E = in_sizes[1];

    // ---- workspace layout (phase-shared, ~259.6 MB for N=1e5,E=6e5) ----
    char* p = (char*)d_ws;
    size_t used = 0;
    auto carve = [&](size_t bytes) {
        char* r = p; size_t a = (bytes + 255) & ~(size_t)255;
        p += a; used += a; return r;
    };
    const size_t nb128 = (size_t)N * 128 * 4;
    float* h    = (float*)carve(nb128);
    float* t1   = (float*)carve(nb128);
    float* dacc = (float*)carve(nb128);
    float* big  = (float*)carve(2 * nb128);       // u / (z | el | er) / ffh
    float* stats= (float*)carve(256 * 4);
    int*   cnt    = (int*)carve((size_t)N * 4);
    int*   rowptr = (int*)carve((size_t)(N + 1) * 4);
    int*   wpos   = (int*)carve((size_t)N * 4);
    int*   esrc   = (int*)carve((size_t)E * 4);
    if (used > ws_size) return;   // diagnostic guard: clean absmax fail instead of fault

    float* u   = big;                       // embed phase (N*128)
    float* z   = big;                       // GAT phase (N*128, first half)
    float* el  = big + (size_t)N * 128;     // GAT phase (N*16, second half)
    float* er  = big + (size_t)N * 144;     // GAT phase (N*16)
    float* ffh = big;                       // FF phase (N*256)

    dim3 b256(256);
    int ecb = (E + 255) / 256;
    int nel = (N * 128 + 255) / 256;
    int gx  = (N + 127) / 128;
    int nwv = (N + 3) / 4;

    // ---- CSR build (incoming edges per node) ----
    zero_i32_k<<<(N + 255) / 256, b256, 0, stream>>>(cnt, N);
    count_k<<<ecb, b256, 0, stream>>>(dst, cnt, E);
    scan_k<<<1, 1024, 0, stream>>>(cnt, rowptr, wpos, N);
    scatter_k<<<ecb, b256, 0, stream>>>(src, dst, wpos, esrc, E);

    // ---- embed: h = relu(x@W1+b1)@W2 + b2 + x@Ws + bs ----
    embed_k<<<nel, b256, 0, stream>>>(x, emb_W1, emb_b1, emb_Ws, emb_bs, u, h, N);
    gemm_k<0,1><<<dim3(gx,1), b256, 0, stream>>>(u, emb_W2, emb_b2, h, N, 128, 128, 128);
    // dec_acc = xs[0] @ dec_W1[0:128] + dec_b1
    gemm_k<0,0><<<dim3(gx,1), b256, 0, stream>>>(h, dec_W1, dec_b1, dacc, N, 128, 128, 128);

    for (int l = 0; l < 4; ++l) {
        // GAT
        gemm_k<0,0><<<dim3(gx,1), b256, 0, stream>>>(h, gat_W + (size_t)l*128*128, nullptr, z, N, 128, 128, 128);
        elr_k<<<(N*16 + 255)/256, b256, 0, stream>>>(z, gat_al + l*128, gat_ar + l*128, el, er, N);
        gat_k<<<nwv, b256, 0, stream>>>(h, z, el, er, rowptr, esrc, gat_b + l*128, t1, N);
        // BN1: h = bn(t1), t1 = same (residual base for FF)
        zero_i32_k<<<1, b256, 0, stream>>>((int*)stats, 256);
        bn_stats_k<<<400, b256, 0, stream>>>(t1, stats, N);
        bn_apply_k<1><<<nel, b256, 0, stream>>>(t1, stats, bn1_g + l*128, bn1_b + l*128, h, t1, N);
        // FF: ffh = relu(h@W1+b1); t1 += ffh@W2 + b2
        gemm_k<1,0><<<dim3(gx,2), b256, 0, stream>>>(h, ff_W1 + (size_t)l*128*256, ff_b1 + l*256, ffh, N, 128, 256, 256);
        gemm_k<0,1><<<dim3(gx,1), b256, 0, stream>>>(ffh, ff_W2 + (size_t)l*256*128, ff_b2 + l*128, t1, N, 256, 128, 128);
        // BN2: h = bn(t1)
        zero_i32_k<<<1, b256, 0, stream>>>((int*)stats, 256);
        bn_stats_k<<<400, b256, 0, stream>>>(t1, stats, N);
        bn_apply_k<0><<<nel, b256, 0, stream>>>(t1, stats, bn2_g + l*128, bn2_b + l*128, h, nullptr, N);
        // dec_acc += xs[l+1] @ dec_W1[(l+1)*128 : ]
        gemm_k<0,1><<<dim3(gx,1), b256, 0, stream>>>(h, dec_W1 + (size_t)(l+1)*128*128, nullptr, dacc, N, 128, 128, 128);
    }

    dec_out_k<<<nwv, b256, 0, stream>>>(dacc, dec_W2, dec_b2, out, N);
}

// Round 3
// 2194.377 us; speedup vs baseline: 1.2634x; 1.2634x over previous
//
#include <hip/hip_runtime.h>
#include <math.h>

typedef __attribute__((ext_vector_type(8))) short bf16x8;
typedef __attribute__((ext_vector_type(4))) float f32x4;

static __device__ __forceinline__ short f2bf(float f) {
    unsigned u = __float_as_uint(f);
    unsigned r = (u + 0x7fffu + ((u >> 16) & 1u)) >> 16;
    return (short)r;
}

// ---------------- zero fill ----------------
__global__ void zero_i32_k(int* __restrict__ p, int n) {
    int i = blockIdx.x * 256 + threadIdx.x;
    if (i < n) p[i] = 0;
}

// ---------------- weight convert+transpose: W[K x Nc] fp32 -> Wt[Nc x K] bf16 ----------------
// grid.y = number of independent slices; slice stride = K*Nc elements in both src and dst.
__global__ __launch_bounds__(256) void wconv_k(const float* __restrict__ W, short* __restrict__ Wt,
                                               int K, int Nc) {
    int slice = blockIdx.y;
    const float* src = W + (size_t)slice * K * Nc;
    short* dst = Wt + (size_t)slice * K * Nc;
    int idx = blockIdx.x * 256 + threadIdx.x;
    if (idx >= K * Nc) return;
    int k = idx / Nc, n = idx - k * Nc;
    dst[(size_t)n * K + k] = f2bf(src[idx]);
}

// ---------------- embed: u = relu(x@W1+b1), h = x@Ws+bs ----------------
__global__ __launch_bounds__(256) void embed_k(
    const float* __restrict__ x, const float* __restrict__ W1, const float* __restrict__ b1,
    const float* __restrict__ Ws, const float* __restrict__ bs,
    float* __restrict__ u, float* __restrict__ h, int Nn)
{
    int idx = blockIdx.x * 256 + threadIdx.x;
    if (idx >= Nn * 128) return;
    int n = idx >> 7, c = idx & 127;
    float x0 = x[2*n], x1 = x[2*n+1];
    float uu = fmaf(x1, W1[128+c], fmaf(x0, W1[c], b1[c]));
    u[idx] = fmaxf(uu, 0.0f);
    h[idx] = fmaf(x1, Ws[128+c], fmaf(x0, Ws[c], bs[c]));
}

// ------- bf16 MFMA GEMM: C (+)= A[Nrows x K](fp32) @ Wt[nc][K](bf16,pretransposed) -------
// 128x128 tile, 256 threads (4 waves), each wave: 2 row-tiles x 8 col-tiles of 16x16x32 MFMA.
template<int RELU, int BETA>
__global__ __launch_bounds__(256) void gemm_mfma_k(
    const float* __restrict__ A, const short* __restrict__ Wt, int ldWt, int kofs,
    const float* __restrict__ bias, float* __restrict__ C,
    int Nrows, int K, int ldC)
{
    __shared__ short As[128][40];  // [row][k], pad 40 -> 80B row stride (16B aligned)
    __shared__ short Bs[128][40];  // [n][k]
    const int row0 = blockIdx.x * 128;
    const int col0 = blockIdx.y * 128;
    const int t = threadIdx.x;
    const int w = t >> 6, lane = t & 63, q = lane >> 4, m = lane & 15;

    f32x4 acc[2][8];
    #pragma unroll
    for (int rb = 0; rb < 2; ++rb)
        #pragma unroll
        for (int cb = 0; cb < 8; ++cb)
            acc[rb][cb] = (f32x4){0.f, 0.f, 0.f, 0.f};

    for (int k0 = 0; k0 < K; k0 += 32) {
        // stage A: 128 rows x 32 k, fp32 -> bf16
        #pragma unroll
        for (int it = 0; it < 4; ++it) {
            int e = (t + it * 256) * 4;
            int r = e >> 5, kk = e & 31;
            int gr = row0 + r;
            float4 v = make_float4(0.f, 0.f, 0.f, 0.f);
            if (gr < Nrows) v = *(const float4*)(A + (size_t)gr * K + k0 + kk);
            short4 s4;
            s4.x = f2bf(v.x); s4.y = f2bf(v.y); s4.z = f2bf(v.z); s4.w = f2bf(v.w);
            *(short4*)&As[r][kk] = s4;
        }
        // stage B: already bf16 [n][k] — straight 16B copies
        #pragma unroll
        for (int it = 0; it < 2; ++it) {
            int e = (t + it * 256) * 8;
            int n = e >> 5, kk = e & 31;
            *(int4*)&Bs[n][kk] = *(const int4*)(Wt + (size_t)(col0 + n) * ldWt + kofs + k0 + kk);
        }
        __syncthreads();
        bf16x8 af[2], bfr[8];
        af[0] = *(bf16x8*)&As[w * 32 + m][q * 8];
        af[1] = *(bf16x8*)&As[w * 32 + 16 + m][q * 8];
        #pragma unroll
        for (int cb = 0; cb < 8; ++cb)
            bfr[cb] = *(bf16x8*)&Bs[cb * 16 + m][q * 8];
        #pragma unroll
        for (int rb = 0; rb < 2; ++rb)
            #pragma unroll
            for (int cb = 0; cb < 8; ++cb)
                acc[rb][cb] = __builtin_amdgcn_mfma_f32_16x16x32_bf16(af[rb], bfr[cb], acc[rb][cb], 0, 0, 0);
        __syncthreads();
    }

    // epilogue: C/D layout col = m, row = q*4 + reg
    #pragma unroll
    for (int rb = 0; rb < 2; ++rb) {
        #pragma unroll
        for (int r = 0; r < 4; ++r) {
            int grow = row0 + w * 32 + rb * 16 + q * 4 + r;
            if (grow >= Nrows) continue;
            #pragma unroll
            for (int cb = 0; cb < 8; ++cb) {
                int gcol = col0 + cb * 16 + m;
                float v = acc[rb][cb][r];
                if (bias) v += bias[gcol];
                size_t off = (size_t)grow * ldC + gcol;
                if (BETA) v += C[off];
                if (RELU) v = fmaxf(v, 0.f);
                C[off] = v;
            }
        }
    }
}

// ---------------- CSR build ----------------
__global__ void count_k(const int* __restrict__ dst, int* __restrict__ cnt, int E) {
    int e = blockIdx.x * 256 + threadIdx.x;
    if (e < E) atomicAdd(&cnt[dst[e]], 1);
}

// parallel scan: per-1024-chunk partial sums
__global__ __launch_bounds__(256) void scan_part_k(const int* __restrict__ cnt,
                                                   int* __restrict__ bsum, int Nn) {
    __shared__ int red[256];
    int base = blockIdx.x * 1024;
    int s = 0;
    for (int i = threadIdx.x; i < 1024; i += 256) {
        int g = base + i;
        if (g < Nn) s += cnt[g];
    }
    red[threadIdx.x] = s; __syncthreads();
    for (int off = 128; off; off >>= 1) {
        if ((int)threadIdx.x < off) red[threadIdx.x] += red[threadIdx.x + off];
        __syncthreads();
    }
    if (threadIdx.x == 0) bsum[blockIdx.x] = red[0];
}

// one-block exclusive scan of block sums (nb <= 256)
__global__ __launch_bounds__(256) void scan_top_k(int* __restrict__ bsum, int nb) {
    __shared__ int buf[256];
    int v = ((int)threadIdx.x < nb) ? bsum[threadIdx.x] : 0;
    buf[threadIdx.x] = v; __syncthreads();
    for (int off = 1; off < 256; off <<= 1) {
        int tv = ((int)threadIdx.x >= off) ? buf[threadIdx.x - off] : 0;
        __syncthreads();
        buf[threadIdx.x] += tv;
        __syncthreads();
    }
    if ((int)threadIdx.x < nb) bsum[threadIdx.x] = buf[threadIdx.x] - v;  // exclusive
}

// apply: per-chunk in-block scan + block offset -> rowptr / wpos
__global__ __launch_bounds__(256) void scan_fin_k(const int* __restrict__ cnt,
    const int* __restrict__ bsum, int* __restrict__ rowptr, int* __restrict__ wpos, int Nn)
{
    __shared__ int tsum[256];
    int base = blockIdx.x * 1024;
    int g0 = base + (int)threadIdx.x * 4;
    int v[4]; int s = 0;
    #pragma unroll
    for (int j = 0; j < 4; ++j) {
        int g = g0 + j;
        v[j] = (g < Nn) ? cnt[g] : 0;
        s += v[j];
    }
    tsum[threadIdx.x] = s; __syncthreads();
    for (int off = 1; off < 256; off <<= 1) {
        int tv = ((int)threadIdx.x >= off) ? tsum[threadIdx.x - off] : 0;
        __syncthreads();
        tsum[threadIdx.x] += tv;
        __syncthreads();
    }
    int run = bsum[blockIdx.x] + tsum[threadIdx.x] - s;  // exclusive prefix at g0
    #pragma unroll
    for (int j = 0; j < 4; ++j) {
        int g = g0 + j;
        if (g < Nn) { wpos[g] = run; rowptr[g + 1] = run + v[j]; }
        run += v[j];
    }
    if (blockIdx.x == 0 && threadIdx.x == 0) rowptr[0] = 0;
}

__global__ void scatter_k(const int* __restrict__ src, const int* __restrict__ dst,
                          int* __restrict__ wpos, int* __restrict__ esrc, int E) {
    int e = blockIdx.x * 256 + threadIdx.x;
    if (e < E) {
        int p = atomicAdd(&wpos[dst[e]], 1);
        esrc[p] = src[e];
    }
}

// ---------------- attention scalars el/er ----------------
__global__ __launch_bounds__(256) void elr_k(const float* __restrict__ z,
    const float* __restrict__ al, const float* __restrict__ ar,
    float* __restrict__ el, float* __restrict__ er, int Nn)
{
    int idx = blockIdx.x * 256 + threadIdx.x;  // n*16 + head
    if (idx >= Nn * 16) return;
    int hd = idx & 15;
    const float* zp = z + (size_t)idx * 8;     // n*128 + hd*8
    float4 z0 = *(const float4*)zp;
    float4 z1 = *(const float4*)(zp + 4);
    float4 a0 = *(const float4*)(al + hd*8);
    float4 a1 = *(const float4*)(al + hd*8 + 4);
    float4 r0 = *(const float4*)(ar + hd*8);
    float4 r1 = *(const float4*)(ar + hd*8 + 4);
    el[idx] = z0.x*a0.x + z0.y*a0.y + z0.z*a0.z + z0.w*a0.w
            + z1.x*a1.x + z1.y*a1.y + z1.z*a1.z + z1.w*a1.w;
    er[idx] = z0.x*r0.x + z0.y*r0.y + z0.z*r0.z + z0.w*r0.w
            + z1.x*r1.x + z1.y*r1.y + z1.z*r1.z + z1.w*r1.w;
}

// ---------------- GAT aggregate: one wave per node, t1 = h + attn + bias ----------------
__global__ __launch_bounds__(256) void gat_k(
    const float* __restrict__ h, const float* __restrict__ z,
    const float* __restrict__ el, const float* __restrict__ er,
    const int* __restrict__ rowptr, const int* __restrict__ esrc,
    const float* __restrict__ gbias, float* __restrict__ t1, int Nn)
{
    int gw = (blockIdx.x * 256 + threadIdx.x) >> 6;  // node = global wave id
    if (gw >= Nn) return;
    int lane = threadIdx.x & 63;
    int n = gw;
    int c = lane * 2;        // 2 channels per lane
    int head = lane >> 2;    // c/8
    float ern = er[n*16 + head];
    int beg = rowptr[n], end = rowptr[n+1];
    float m = -1e30f;
    for (int i = beg; i < end; ++i) {
        int s = esrc[i];
        float e = el[s*16 + head] + ern;
        e = (e > 0.f) ? e : 0.2f * e;
        m = fmaxf(m, e);
    }
    float den = 0.f, a0 = 0.f, a1 = 0.f;
    for (int i = beg; i < end; ++i) {
        int s = esrc[i];
        float e = el[s*16 + head] + ern;
        e = (e > 0.f) ? e : 0.2f * e;
        float w = __expf(e - m);
        float2 zz = *(const float2*)(z + (size_t)s*128 + c);
        den += w;
        a0 = fmaf(w, zz.x, a0);
        a1 = fmaf(w, zz.y, a1);
    }
    float inv = 1.f / den;
    size_t o = (size_t)n*128 + c;
    float2 hh = *(const float2*)(h + o);
    float2 r;
    r.x = hh.x + a0*inv + gbias[c];
    r.y = hh.y + a1*inv + gbias[c+1];
    *(float2*)(t1 + o) = r;
}

// ---------------- BatchNorm (training mode, biased var) ----------------
__global__ __launch_bounds__(256) void bn_stats_k(const float* __restrict__ xin,
    float* __restrict__ stats, int Nn)
{
    __shared__ float ss[256], sq[256];
    int c = threadIdx.x & 127;
    int half = threadIdx.x >> 7;
    float s = 0.f, q = 0.f;
    for (int r = blockIdx.x*2 + half; r < Nn; r += gridDim.x*2) {
        float v = xin[(size_t)r*128 + c];
        s += v; q = fmaf(v, v, q);
    }
    ss[threadIdx.x] = s; sq[threadIdx.x] = q;
    __syncthreads();
    if (half == 0) {
        atomicAdd(&stats[c],     ss[c] + ss[c+128]);
        atomicAdd(&stats[128+c], sq[c] + sq[c+128]);
    }
}

template<int WRITE2>
__global__ __launch_bounds__(256) void bn_apply_k(const float* __restrict__ xin,
    const float* __restrict__ stats, const float* __restrict__ g, const float* __restrict__ b,
    float* __restrict__ hout, float* __restrict__ t1out, int Nn)
{
    int idx = blockIdx.x * 256 + threadIdx.x;
    if (idx >= Nn * 128) return;
    int c = idx & 127;
    float invN = 1.f / (float)Nn;
    float mu = stats[c] * invN;
    float var = stats[128+c] * invN - mu*mu;
    float y = (xin[idx] - mu) * rsqrtf(var + 1e-5f) * g[c] + b[c];
    hout[idx] = y;
    if (WRITE2) t1out[idx] = y;
}

// ---------------- decoder output: out[n] = relu(dacc[n,:]) . W2 + b2 ----------------
__global__ __launch_bounds__(256) void dec_out_k(const float* __restrict__ dacc,
    const float* __restrict__ W2, const float* __restrict__ b2,
    float* __restrict__ out, int Nn)
{
    int gw = (blockIdx.x * 256 + threadIdx.x) >> 6;
    if (gw >= Nn) return;
    int lane = threadIdx.x & 63;
    const float* row = dacc + (size_t)gw * 128;
    float v0 = fmaxf(row[lane],      0.f);
    float v1 = fmaxf(row[64 + lane], 0.f);
    float p = v0 * W2[lane] + v1 * W2[64 + lane];
    #pragma unroll
    for (int off = 32; off > 0; off >>= 1) p += __shfl_down(p, off);
    if (lane == 0) out[gw] = p + b2[0];
}

extern "C" void kernel_launch(void* const* d_in, const int* in_sizes, int n_in,
                              void* d_out, int out_size, void* d_ws, size_t ws_size,
                              hipStream_t stream)
{
    const float* x      = (const float*)d_in[0];
    const int*   src    = (const int*)  d_in[1];
    const int*   dst    = (const int*)  d_in[2];
    const float* emb_W1 = (const float*)d_in[3];
    const float* emb_b1 = (const float*)d_in[4];
    const float* emb_W2 = (const float*)d_in[5];
    const float* emb_b2 = (const float*)d_in[6];
    const float* emb_Ws = (const float*)d_in[7];
    const float* emb_bs = (const float*)d_in[8];
    const float* gat_W  = (const float*)d_in[9];
    const float* gat_al = (const float*)d_in[10];
    const float* gat_ar = (const float*)d_in[11];
    const float* gat_b  = (const float*)d_in[12];
    const float* bn1_g  = (const float*)d_in[13];
    const float* bn1_b  = (const float*)d_in[14];
    const float* ff_W1  = (const float*)d_in[15];
    const float* ff_b1  = (const float*)d_in[16];
    const float* ff_W2  = (const float*)d_in[17];
    const float* ff_b2  = (const float*)d_in[18];
    const float* bn2_g  = (const float*)d_in[19];
    const float* bn2_b  = (const float*)d_in[20];
    const float* dec_W1 = (const float*)d_in[21];
    const float* dec_b1 = (const float*)d_in[22];
    const float* dec_W2 = (const float*)d_in[23];
    const float* dec_b2 = (const float*)d_in[24];
    float* out = (float*)d_out;
    (void)n_in; (void)out_size;

    const int N = in_sizes[0] / 2;
    const int E = in_sizes[1];

    // ---- workspace layout ----
    char* p = (char*)d_ws;
    size_t used = 0;
    auto carve = [&](size_t bytes) {
        char* r = p; size_t a = (bytes + 255) & ~(size_t)255;
        p += a; used += a; return r;
    };
    const size_t nb128 = (size_t)N * 128 * 4;
    float* h    = (float*)carve(nb128);
    float* t1   = (float*)carve(nb128);
    float* dacc = (float*)carve(nb128);
    float* big  = (float*)carve(2 * nb128);       // u / (z | el | er) / ffh
    float* stats= (float*)carve(256 * 4);
    int*   cnt    = (int*)carve((size_t)N * 4);
    int*   rowptr = (int*)carve((size_t)(N + 1) * 4);
    int*   wpos   = (int*)carve((size_t)N * 4);
    int*   esrc   = (int*)carve((size_t)E * 4);
    int*   bsum   = (int*)carve(256 * 4);
    // bf16 pre-transposed weights
    short* emb_W2t = (short*)carve((size_t)128 * 128 * 2);
    short* gat_Wt  = (short*)carve((size_t)4 * 128 * 128 * 2);
    short* ff_W1t  = (short*)carve((size_t)4 * 128 * 256 * 2);
    short* ff_W2t  = (short*)carve((size_t)4 * 256 * 128 * 2);
    short* dec_W1t = (short*)carve((size_t)640 * 128 * 2);
    if (used > ws_size) return;   // diagnostic guard

    float* u   = big;                       // embed phase (N*128)
    float* z   = big;                       // GAT phase (N*128)
    float* el  = big + (size_t)N * 128;     // GAT phase (N*16)
    float* er  = big + (size_t)N * 144;     // GAT phase (N*16)
    float* ffh = big;                       // FF phase (N*256)

    dim3 b256(256);
    int ecb = (E + 255) / 256;
    int nel = (N * 128 + 255) / 256;
    int gx  = (N + 127) / 128;
    int nwv = (N + 3) / 4;
    int nb  = (N + 1023) / 1024;

    // ---- weight convert + transpose (bf16) ----
    wconv_k<<<dim3(64, 1), b256, 0, stream>>>(emb_W2, emb_W2t, 128, 128);
    wconv_k<<<dim3(64, 4), b256, 0, stream>>>(gat_W,  gat_Wt,  128, 128);
    wconv_k<<<dim3(128, 4), b256, 0, stream>>>(ff_W1, ff_W1t,  128, 256);
    wconv_k<<<dim3(128, 4), b256, 0, stream>>>(ff_W2, ff_W2t,  256, 128);
    wconv_k<<<dim3(320, 1), b256, 0, stream>>>(dec_W1, dec_W1t, 640, 128);

    // ---- CSR build (incoming edges per node) ----
    zero_i32_k<<<(N + 255) / 256, b256, 0, stream>>>(cnt, N);
    count_k<<<ecb, b256, 0, stream>>>(dst, cnt, E);
    scan_part_k<<<nb, b256, 0, stream>>>(cnt, bsum, N);
    scan_top_k<<<1, b256, 0, stream>>>(bsum, nb);
    scan_fin_k<<<nb, b256, 0, stream>>>(cnt, bsum, rowptr, wpos, N);
    scatter_k<<<ecb, b256, 0, stream>>>(src, dst, wpos, esrc, E);

    // ---- embed: h = relu(x@W1+b1)@W2 + b2 + x@Ws + bs ----
    embed_k<<<nel, b256, 0, stream>>>(x, emb_W1, emb_b1, emb_Ws, emb_bs, u, h, N);
    gemm_mfma_k<0,1><<<dim3(gx,1), b256, 0, stream>>>(u, emb_W2t, 128, 0, emb_b2, h, N, 128, 128);
    // dec_acc = xs[0] @ dec_W1[0:128] + dec_b1
    gemm_mfma_k<0,0><<<dim3(gx,1), b256, 0, stream>>>(h, dec_W1t, 640, 0, dec_b1, dacc, N, 128, 128);

    for (int l = 0; l < 4; ++l) {
        // GAT
        gemm_mfma_k<0,0><<<dim3(gx,1), b256, 0, stream>>>(h, gat_Wt + (size_t)l*128*128, 128, 0, nullptr, z, N, 128, 128);
        elr_k<<<(N*16 + 255)/256, b256, 0, stream>>>(z, gat_al + l*128, gat_ar + l*128, el, er, N);
        gat_k<<<nwv, b256, 0, stream>>>(h, z, el, er, rowptr, esrc, gat_b + l*128, t1, N);
        // BN1: h = bn(t1), t1 = same (residual base for FF)
        zero_i32_k<<<1, b256, 0, stream>>>((int*)stats, 256);
        bn_stats_k<<<400, b256, 0, stream>>>(t1, stats, N);
        bn_apply_k<1><<<nel, b256, 0, stream>>>(t1, stats, bn1_g + l*128, bn1_b + l*128, h, t1, N);
        // FF: ffh = relu(h@W1+b1); t1 += ffh@W2 + b2
        gemm_mfma_k<1,0><<<dim3(gx,2), b256, 0, stream>>>(h, ff_W1t + (size_t)l*128*256, 128, 0, ff_b1 + l*256, ffh, N, 128, 256);
        gemm_mfma_k<0,1><<<dim3(gx,1), b256, 0, stream>>>(ffh, ff_W2t + (size_t)l*256*128, 256, 0, ff_b2 + l*128, t1, N, 256, 128);
        // BN2: h = bn(t1)
        zero_i32_k<<<1, b256, 0, stream>>>((int*)stats, 256);
        bn_stats_k<<<400, b256, 0, stream>>>(t1, stats, N);
        bn_apply_k<0><<<nel, b256, 0, stream>>>(t1, stats, bn2_g + l*128, bn2_b + l*128, h, nullptr, N);
        // dec_acc += xs[l+1] @ dec_W1 slice
        gemm_mfma_k<0,1><<<dim3(gx,1), b256, 0, stream>>>(h, dec_W1t, 640, (l+1)*128, nullptr, dacc, N, 128, 128);
    }

    dec_out_k<<<nwv, b256, 0, stream>>>(dacc, dec_W2, dec_b2, out, N);
}

// Round 4
// 1861.128 us; speedup vs baseline: 1.4897x; 1.1791x over previous
//
#include <hip/hip_runtime.h>
#include <math.h>

typedef __attribute__((ext_vector_type(8))) short bf16x8;
typedef __attribute__((ext_vector_type(4))) float f32x4;

static __device__ __forceinline__ short f2bf(float f) {
    unsigned u = __float_as_uint(f);
    unsigned r = (u + 0x7fffu + ((u >> 16) & 1u)) >> 16;
    return (short)r;
}
static __device__ __forceinline__ float bf2f(short s) {
    return __uint_as_float(((unsigned)(unsigned short)s) << 16);
}
static __device__ __forceinline__ int pack2(float a, float b) {
    return (int)(((unsigned)(unsigned short)f2bf(b) << 16) | (unsigned)(unsigned short)f2bf(a));
}

// ---------------- zero fill ----------------
__global__ void zero_i32_k(int* __restrict__ p, int n) {
    int i = blockIdx.x * 256 + threadIdx.x;
    if (i < n) p[i] = 0;
}

// ---------------- weight convert+transpose: W[K x Nc] fp32 -> Wt[Nc x K] bf16 ----------------
__global__ __launch_bounds__(256) void wconv_k(const float* __restrict__ W, short* __restrict__ Wt,
                                               int K, int Nc) {
    int slice = blockIdx.y;
    const float* src = W + (size_t)slice * K * Nc;
    short* dst = Wt + (size_t)slice * K * Nc;
    int idx = blockIdx.x * 256 + threadIdx.x;
    if (idx >= K * Nc) return;
    int k = idx / Nc, n = idx - k * Nc;
    dst[(size_t)n * K + k] = f2bf(src[idx]);
}

// ---------------- embed: u = relu(x@W1+b1), h = x@Ws+bs (both bf16) ----------------
__global__ __launch_bounds__(256) void embed_k(
    const float* __restrict__ x, const float* __restrict__ W1, const float* __restrict__ b1,
    const float* __restrict__ Ws, const float* __restrict__ bs,
    int* __restrict__ u2, int* __restrict__ h2, int Nn)
{
    int idx = blockIdx.x * 256 + threadIdx.x;
    if (idx >= Nn * 64) return;
    int n = idx >> 6, c = (idx & 63) * 2;
    float x0 = x[2*n], x1 = x[2*n+1];
    float u0 = fmaxf(fmaf(x1, W1[128+c],   fmaf(x0, W1[c],   b1[c])),   0.f);
    float u1 = fmaxf(fmaf(x1, W1[128+c+1], fmaf(x0, W1[c+1], b1[c+1])), 0.f);
    float h0 = fmaf(x1, Ws[128+c],   fmaf(x0, Ws[c],   bs[c]));
    float h1 = fmaf(x1, Ws[128+c+1], fmaf(x0, Ws[c+1], bs[c+1]));
    u2[idx] = pack2(u0, u1);
    h2[idx] = pack2(h0, h1);
}

// ------- bf16 MFMA GEMM: C (+)= A[Nrows x K](bf16) @ Wt[nc][K](bf16) -------
// 128x128 tile, 256 threads (4 waves), wave: 2 row-tiles x 8 col-tiles of 16x16x32 MFMA.
// CF32: C is fp32 (dacc) else bf16.
template<int RELU, int BETA, int CF32>
__global__ __launch_bounds__(256) void gemm_mfma_k(
    const short* __restrict__ A, const short* __restrict__ Wt, int ldWt, int kofs,
    const float* __restrict__ bias, void* __restrict__ Cv,
    int Nrows, int K, int ldC)
{
    __shared__ short As[128][40];  // pad 40 -> 80B row stride (16B aligned, 2-way banks only)
    __shared__ short Bs[128][40];
    const int row0 = blockIdx.x * 128;
    const int col0 = blockIdx.y * 128;
    const int t = threadIdx.x;
    const int w = t >> 6, lane = t & 63, q = lane >> 4, m = lane & 15;

    f32x4 acc[2][8];
    #pragma unroll
    for (int rb = 0; rb < 2; ++rb)
        #pragma unroll
        for (int cb = 0; cb < 8; ++cb)
            acc[rb][cb] = (f32x4){0.f, 0.f, 0.f, 0.f};

    for (int k0 = 0; k0 < K; k0 += 32) {
        // stage A: 128 rows x 32 k bf16 = 8KB, 2 x int4 per thread
        #pragma unroll
        for (int it = 0; it < 2; ++it) {
            int ci = t + it * 256;          // 0..511
            int r = ci >> 2, kk = (ci & 3) * 8;
            int gr = row0 + r;
            int4 v = make_int4(0, 0, 0, 0);
            if (gr < Nrows) v = *(const int4*)(A + (size_t)gr * K + k0 + kk);
            *(int4*)&As[r][kk] = v;
        }
        // stage B
        #pragma unroll
        for (int it = 0; it < 2; ++it) {
            int ci = t + it * 256;
            int n = ci >> 2, kk = (ci & 3) * 8;
            *(int4*)&Bs[n][kk] = *(const int4*)(Wt + (size_t)(col0 + n) * ldWt + kofs + k0 + kk);
        }
        __syncthreads();
        bf16x8 af[2], bfr[8];
        af[0] = *(bf16x8*)&As[w * 32 + m][q * 8];
        af[1] = *(bf16x8*)&As[w * 32 + 16 + m][q * 8];
        #pragma unroll
        for (int cb = 0; cb < 8; ++cb)
            bfr[cb] = *(bf16x8*)&Bs[cb * 16 + m][q * 8];
        #pragma unroll
        for (int rb = 0; rb < 2; ++rb)
            #pragma unroll
            for (int cb = 0; cb < 8; ++cb)
                acc[rb][cb] = __builtin_amdgcn_mfma_f32_16x16x32_bf16(af[rb], bfr[cb], acc[rb][cb], 0, 0, 0);
        __syncthreads();
    }

    float* Cf = (float*)Cv;
    short* Cs = (short*)Cv;
    #pragma unroll
    for (int rb = 0; rb < 2; ++rb) {
        #pragma unroll
        for (int r = 0; r < 4; ++r) {
            int grow = row0 + w * 32 + rb * 16 + q * 4 + r;
            if (grow >= Nrows) continue;
            #pragma unroll
            for (int cb = 0; cb < 8; ++cb) {
                int gcol = col0 + cb * 16 + m;
                float v = acc[rb][cb][r];
                if (bias) v += bias[gcol];
                size_t off = (size_t)grow * ldC + gcol;
                if (BETA) v += CF32 ? Cf[off] : bf2f(Cs[off]);
                if (RELU) v = fmaxf(v, 0.f);
                if (CF32) Cf[off] = v; else Cs[off] = f2bf(v);
            }
        }
    }
}

// ---------------- CSR build ----------------
__global__ void count_k(const int* __restrict__ dst, int* __restrict__ cnt, int E) {
    int e = blockIdx.x * 256 + threadIdx.x;
    if (e < E) atomicAdd(&cnt[dst[e]], 1);
}

__global__ __launch_bounds__(256) void scan_part_k(const int* __restrict__ cnt,
                                                   int* __restrict__ bsum, int Nn) {
    __shared__ int red[256];
    int base = blockIdx.x * 1024;
    int s = 0;
    for (int i = threadIdx.x; i < 1024; i += 256) {
        int g = base + i;
        if (g < Nn) s += cnt[g];
    }
    red[threadIdx.x] = s; __syncthreads();
    for (int off = 128; off; off >>= 1) {
        if ((int)threadIdx.x < off) red[threadIdx.x] += red[threadIdx.x + off];
        __syncthreads();
    }
    if (threadIdx.x == 0) bsum[blockIdx.x] = red[0];
}

__global__ __launch_bounds__(256) void scan_top_k(int* __restrict__ bsum, int nb) {
    __shared__ int buf[256];
    int v = ((int)threadIdx.x < nb) ? bsum[threadIdx.x] : 0;
    buf[threadIdx.x] = v; __syncthreads();
    for (int off = 1; off < 256; off <<= 1) {
        int tv = ((int)threadIdx.x >= off) ? buf[threadIdx.x - off] : 0;
        __syncthreads();
        buf[threadIdx.x] += tv;
        __syncthreads();
    }
    if ((int)threadIdx.x < nb) bsum[threadIdx.x] = buf[threadIdx.x] - v;
}

__global__ __launch_bounds__(256) void scan_fin_k(const int* __restrict__ cnt,
    const int* __restrict__ bsum, int* __restrict__ rowptr, int* __restrict__ wpos, int Nn)
{
    __shared__ int tsum[256];
    int base = blockIdx.x * 1024;
    int g0 = base + (int)threadIdx.x * 4;
    int v[4]; int s = 0;
    #pragma unroll
    for (int j = 0; j < 4; ++j) {
        int g = g0 + j;
        v[j] = (g < Nn) ? cnt[g] : 0;
        s += v[j];
    }
    tsum[threadIdx.x] = s; __syncthreads();
    for (int off = 1; off < 256; off <<= 1) {
        int tv = ((int)threadIdx.x >= off) ? tsum[threadIdx.x - off] : 0;
        __syncthreads();
        tsum[threadIdx.x] += tv;
        __syncthreads();
    }
    int run = bsum[blockIdx.x] + tsum[threadIdx.x] - s;
    #pragma unroll
    for (int j = 0; j < 4; ++j) {
        int g = g0 + j;
        if (g < Nn) { wpos[g] = run; rowptr[g + 1] = run + v[j]; }
        run += v[j];
    }
    if (blockIdx.x == 0 && threadIdx.x == 0) rowptr[0] = 0;
}

__global__ void scatter_k(const int* __restrict__ src, const int* __restrict__ dst,
                          int* __restrict__ wpos, int* __restrict__ esrc, int E) {
    int e = blockIdx.x * 256 + threadIdx.x;
    if (e < E) {
        int p = atomicAdd(&wpos[dst[e]], 1);
        esrc[p] = src[e];
    }
}

// ---------------- attention scalars el/er (z bf16) ----------------
__global__ __launch_bounds__(256) void elr_k(const short* __restrict__ z,
    const float* __restrict__ al, const float* __restrict__ ar,
    float* __restrict__ el, float* __restrict__ er, int Nn)
{
    int idx = blockIdx.x * 256 + threadIdx.x;  // n*16 + head
    if (idx >= Nn * 16) return;
    int hd = idx & 15;
    int4 zv = *(const int4*)(z + (size_t)idx * 8);
    float zf[8];
    zf[0] = bf2f((short)(zv.x & 0xffff)); zf[1] = bf2f((short)(zv.x >> 16));
    zf[2] = bf2f((short)(zv.y & 0xffff)); zf[3] = bf2f((short)(zv.y >> 16));
    zf[4] = bf2f((short)(zv.z & 0xffff)); zf[5] = bf2f((short)(zv.z >> 16));
    zf[6] = bf2f((short)(zv.w & 0xffff)); zf[7] = bf2f((short)(zv.w >> 16));
    float sl = 0.f, sr = 0.f;
    #pragma unroll
    for (int j = 0; j < 8; ++j) {
        sl = fmaf(zf[j], al[hd*8 + j], sl);
        sr = fmaf(zf[j], ar[hd*8 + j], sr);
    }
    el[idx] = sl; er[idx] = sr;
}

// ---------------- GAT aggregate: one wave per node (h,z,t1 bf16) ----------------
__global__ __launch_bounds__(256) void gat_k(
    const short* __restrict__ h, const short* __restrict__ z,
    const float* __restrict__ el, const float* __restrict__ er,
    const int* __restrict__ rowptr, const int* __restrict__ esrc,
    const float* __restrict__ gbias, short* __restrict__ t1, int Nn)
{
    int gw = (blockIdx.x * 256 + threadIdx.x) >> 6;
    if (gw >= Nn) return;
    int lane = threadIdx.x & 63;
    int n = gw;
    int c = lane * 2;
    int head = lane >> 2;
    float ern = er[n*16 + head];
    int beg = rowptr[n], end = rowptr[n+1];
    float m = -1e30f;
    for (int i = beg; i < end; ++i) {
        int s = esrc[i];
        float e = el[s*16 + head] + ern;
        e = (e > 0.f) ? e : 0.2f * e;
        m = fmaxf(m, e);
    }
    float den = 0.f, a0 = 0.f, a1 = 0.f;
    for (int i = beg; i < end; ++i) {
        int s = esrc[i];
        float e = el[s*16 + head] + ern;
        e = (e > 0.f) ? e : 0.2f * e;
        float w = __expf(e - m);
        int zz = *(const int*)(z + (size_t)s*128 + c);
        den += w;
        a0 = fmaf(w, bf2f((short)(zz & 0xffff)), a0);
        a1 = fmaf(w, bf2f((short)(zz >> 16)),    a1);
    }
    float inv = 1.f / den;
    size_t o = (size_t)n*64 + lane;
    int hv = ((const int*)h)[o];
    float r0 = bf2f((short)(hv & 0xffff)) + a0*inv + gbias[c];
    float r1 = bf2f((short)(hv >> 16))    + a1*inv + gbias[c+1];
    ((int*)t1)[o] = pack2(r0, r1);
}

// ---------------- BatchNorm (bf16 in, fp32 stats) ----------------
__global__ __launch_bounds__(256) void bn_stats_k(const short* __restrict__ xin,
    float* __restrict__ stats, int Nn)
{
    __shared__ float s0s[256], s1s[256], q0s[256], q1s[256];
    int pair = threadIdx.x & 63;     // channels 2*pair, 2*pair+1
    int slot = threadIdx.x >> 6;
    float s0 = 0.f, s1 = 0.f, q0 = 0.f, q1 = 0.f;
    for (int r = blockIdx.x*4 + slot; r < Nn; r += gridDim.x*4) {
        int v = *(const int*)(xin + (size_t)r*128 + pair*2);
        float a = bf2f((short)(v & 0xffff));
        float b = bf2f((short)(v >> 16));
        s0 += a; s1 += b;
        q0 = fmaf(a, a, q0); q1 = fmaf(b, b, q1);
    }
    s0s[threadIdx.x] = s0; s1s[threadIdx.x] = s1;
    q0s[threadIdx.x] = q0; q1s[threadIdx.x] = q1;
    __syncthreads();
    if (slot == 0) {
        #pragma unroll
        for (int j = 1; j < 4; ++j) {
            s0 += s0s[pair + j*64]; s1 += s1s[pair + j*64];
            q0 += q0s[pair + j*64]; q1 += q1s[pair + j*64];
        }
        atomicAdd(&stats[pair*2],       s0);
        atomicAdd(&stats[pair*2+1],     s1);
        atomicAdd(&stats[128+pair*2],   q0);
        atomicAdd(&stats[128+pair*2+1], q1);
    }
}

template<int WRITE2>
__global__ __launch_bounds__(256) void bn_apply_k(const short* __restrict__ xin,
    const float* __restrict__ stats, const float* __restrict__ g, const float* __restrict__ b,
    short* __restrict__ hout, short* __restrict__ t1out, int Nn)
{
    int idx = blockIdx.x * 256 + threadIdx.x;
    if (idx >= Nn * 64) return;
    int c = (idx & 63) * 2;
    float invN = 1.f / (float)Nn;
    float mu0 = stats[c] * invN,   mu1 = stats[c+1] * invN;
    float v0 = stats[128+c] * invN - mu0*mu0;
    float v1 = stats[128+c+1] * invN - mu1*mu1;
    float sc0 = rsqrtf(v0 + 1e-5f) * g[c],   sc1 = rsqrtf(v1 + 1e-5f) * g[c+1];
    int v = ((const int*)xin)[idx];
    float y0 = (bf2f((short)(v & 0xffff)) - mu0) * sc0 + b[c];
    float y1 = (bf2f((short)(v >> 16))    - mu1) * sc1 + b[c+1];
    int pk = pack2(y0, y1);
    ((int*)hout)[idx] = pk;
    if (WRITE2) ((int*)t1out)[idx] = pk;
}

// ---------------- decoder output ----------------
__global__ __launch_bounds__(256) void dec_out_k(const float* __restrict__ dacc,
    const float* __restrict__ W2, const float* __restrict__ b2,
    float* __restrict__ out, int Nn)
{
    int gw = (blockIdx.x * 256 + threadIdx.x) >> 6;
    if (gw >= Nn) return;
    int lane = threadIdx.x & 63;
    const float* row = dacc + (size_t)gw * 128;
    float v0 = fmaxf(row[lane],      0.f);
    float v1 = fmaxf(row[64 + lane], 0.f);
    float p = v0 * W2[lane] + v1 * W2[64 + lane];
    #pragma unroll
    for (int off = 32; off > 0; off >>= 1) p += __shfl_down(p, off);
    if (lane == 0) out[gw] = p + b2[0];
}

extern "C" void kernel_launch(void* const* d_in, const int* in_sizes, int n_in,
                              void* d_out, int out_size, void* d_ws, size_t ws_size,
                              hipStream_t stream)
{
    const float* x      = (const float*)d_in[0];
    const int*   src    = (const int*)  d_in[1];
    const int*   dst    = (const int*)  d_in[2];
    const float* emb_W1 = (const float*)d_in[3];
    const float* emb_b1 = (const float*)d_in[4];
    const float* emb_W2 = (const float*)d_in[5];
    const float* emb_b2 = (const float*)d_in[6];
    const float* emb_Ws = (const float*)d_in[7];
    const float* emb_bs = (const float*)d_in[8];
    const float* gat_W  = (const float*)d_in[9];
    const float* gat_al = (const float*)d_in[10];
    const float* gat_ar = (const float*)d_in[11];
    const float* gat_b  = (const float*)d_in[12];
    const float* bn1_g  = (const float*)d_in[13];
    const float* bn1_b  = (const float*)d_in[14];
    const float* ff_W1  = (const float*)d_in[15];
    const float* ff_b1  = (const float*)d_in[16];
    const float* ff_W2  = (const float*)d_in[17];
    const float* ff_b2  = (const float*)d_in[18];
    const float* bn2_g  = (const float*)d_in[19];
    const float* bn2_b  = (const float*)d_in[20];
    const float* dec_W1 = (const float*)d_in[21];
    const float* dec_b1 = (const float*)d_in[22];
    const float* dec_W2 = (const float*)d_in[23];
    const float* dec_b2 = (const float*)d_in[24];
    float* out = (float*)d_out;
    (void)n_in; (void)out_size;

    const int N = in_sizes[0] / 2;
    const int E = in_sizes[1];

    // ---- workspace ----
    char* p = (char*)d_ws;
    size_t used = 0;
    auto carve = [&](size_t bytes) {
        char* r = p; size_t a = (bytes + 255) & ~(size_t)255;
        p += a; used += a; return r;
    };
    const size_t nb128 = (size_t)N * 128 * 4;
    short* h    = (short*)carve(nb128 / 2);
    short* t1   = (short*)carve(nb128 / 2);
    float* dacc = (float*)carve(nb128);
    char*  big  = (char*)carve(nb128);     // u / (z | el | er) / ffh  (bf16 phases)
    float* stats= (float*)carve(256 * 4);
    int*   cnt    = (int*)carve((size_t)N * 4);
    int*   rowptr = (int*)carve((size_t)(N + 1) * 4);
    int*   wpos   = (int*)carve((size_t)N * 4);
    int*   esrc   = (int*)carve((size_t)E * 4);
    int*   bsum   = (int*)carve(256 * 4);
    short* emb_W2t = (short*)carve((size_t)128 * 128 * 2);
    short* gat_Wt  = (short*)carve((size_t)4 * 128 * 128 * 2);
    short* ff_W1t  = (short*)carve((size_t)4 * 128 * 256 * 2);
    short* ff_W2t  = (short*)carve((size_t)4 * 256 * 128 * 2);
    short* dec_W1t = (short*)carve((size_t)640 * 128 * 2);
    if (used > ws_size) return;

    short* u   = (short*)big;
    short* z   = (short*)big;
    float* el  = (float*)(big + (size_t)N * 128 * 2);
    float* er  = el + (size_t)N * 16;
    short* ffh = (short*)big;

    dim3 b256(256);
    int ecb  = (E + 255) / 256;
    int nel2 = (N * 64 + 255) / 256;
    int gx   = (N + 127) / 128;
    int nwv  = (N + 3) / 4;
    int nb   = (N + 1023) / 1024;

    // ---- weight convert + transpose ----
    wconv_k<<<dim3(64, 1), b256, 0, stream>>>(emb_W2, emb_W2t, 128, 128);
    wconv_k<<<dim3(64, 4), b256, 0, stream>>>(gat_W,  gat_Wt,  128, 128);
    wconv_k<<<dim3(128, 4), b256, 0, stream>>>(ff_W1, ff_W1t,  128, 256);
    wconv_k<<<dim3(128, 4), b256, 0, stream>>>(ff_W2, ff_W2t,  256, 128);
    wconv_k<<<dim3(320, 1), b256, 0, stream>>>(dec_W1, dec_W1t, 640, 128);

    // ---- CSR build ----
    zero_i32_k<<<(N + 255) / 256, b256, 0, stream>>>(cnt, N);
    count_k<<<ecb, b256, 0, stream>>>(dst, cnt, E);
    scan_part_k<<<nb, b256, 0, stream>>>(cnt, bsum, N);
    scan_top_k<<<1, b256, 0, stream>>>(bsum, nb);
    scan_fin_k<<<nb, b256, 0, stream>>>(cnt, bsum, rowptr, wpos, N);
    scatter_k<<<ecb, b256, 0, stream>>>(src, dst, wpos, esrc, E);

    // ---- embed ----
    embed_k<<<nel2, b256, 0, stream>>>(x, emb_W1, emb_b1, emb_Ws, emb_bs, (int*)u, (int*)h, N);
    gemm_mfma_k<0,1,0><<<dim3(gx,1), b256, 0, stream>>>(u, emb_W2t, 128, 0, emb_b2, h, N, 128, 128);
    gemm_mfma_k<0,0,1><<<dim3(gx,1), b256, 0, stream>>>(h, dec_W1t, 640, 0, dec_b1, dacc, N, 128, 128);

    for (int l = 0; l < 4; ++l) {
        gemm_mfma_k<0,0,0><<<dim3(gx,1), b256, 0, stream>>>(h, gat_Wt + (size_t)l*128*128, 128, 0, nullptr, z, N, 128, 128);
        elr_k<<<(N*16 + 255)/256, b256, 0, stream>>>(z, gat_al + l*128, gat_ar + l*128, el, er, N);
        gat_k<<<nwv, b256, 0, stream>>>(h, z, el, er, rowptr, esrc, gat_b + l*128, t1, N);
        zero_i32_k<<<1, b256, 0, stream>>>((int*)stats, 256);
        bn_stats_k<<<400, b256, 0, stream>>>(t1, stats, N);
        bn_apply_k<1><<<nel2, b256, 0, stream>>>(t1, stats, bn1_g + l*128, bn1_b + l*128, h, t1, N);
        gemm_mfma_k<1,0,0><<<dim3(gx,2), b256, 0, stream>>>(h, ff_W1t + (size_t)l*128*256, 128, 0, ff_b1 + l*256, ffh, N, 128, 256);
        gemm_mfma_k<0,1,0><<<dim3(gx,1), b256, 0, stream>>>(ffh, ff_W2t + (size_t)l*256*128, 256, 0, ff_b2 + l*128, t1, N, 256, 128);
        zero_i32_k<<<1, b256, 0, stream>>>((int*)stats, 256);
        bn_stats_k<<<400, b256, 0, stream>>>(t1, stats, N);
        bn_apply_k<0><<<nel2, b256, 0, stream>>>(t1, stats, bn2_g + l*128, bn2_b + l*128, h, nullptr, N);
        gemm_mfma_k<0,1,1><<<dim3(gx,1), b256, 0, stream>>>(h, dec_W1t, 640, (l+1)*128, nullptr, dacc, N, 128, 128);
    }

    dec_out_k<<<nwv, b256, 0, stream>>>(dacc, dec_W2, dec_b2, out, N);
}

// Round 5
// 1620.019 us; speedup vs baseline: 1.7114x; 1.1488x over previous
//
#include <hip/hip_runtime.h>
#include <math.h>

typedef __attribute__((ext_vector_type(8))) short bf16x8;
typedef __attribute__((ext_vector_type(4))) float f32x4;

static __device__ __forceinline__ short f2bf(float f) {
    unsigned u = __float_as_uint(f);
    unsigned r = (u + 0x7fffu + ((u >> 16) & 1u)) >> 16;
    return (short)r;
}
static __device__ __forceinline__ float bf2f(short s) {
    return __uint_as_float(((unsigned)(unsigned short)s) << 16);
}
static __device__ __forceinline__ float bflo(int v) { return bf2f((short)(v & 0xffff)); }
static __device__ __forceinline__ float bfhi(int v) { return bf2f((short)(((unsigned)v) >> 16)); }
static __device__ __forceinline__ int pack2(float a, float b) {
    return (int)(((unsigned)(unsigned short)f2bf(b) << 16) | (unsigned)(unsigned short)f2bf(a));
}

// ---------------- zero fill ----------------
__global__ void zero_i32_k(int* __restrict__ p, int n) {
    int i = blockIdx.x * 256 + threadIdx.x;
    if (i < n) p[i] = 0;
}

// ---------------- weight convert+transpose: W[K x Nc] fp32 -> Wt[Nc x K] bf16 ----------------
__global__ __launch_bounds__(256) void wconv_k(const float* __restrict__ W, short* __restrict__ Wt,
                                               int K, int Nc) {
    int slice = blockIdx.y;
    const float* src = W + (size_t)slice * K * Nc;
    short* dst = Wt + (size_t)slice * K * Nc;
    int idx = blockIdx.x * 256 + threadIdx.x;
    if (idx >= K * Nc) return;
    int k = idx / Nc, n = idx - k * Nc;
    dst[(size_t)n * K + k] = f2bf(src[idx]);
}

// ---------------- embed: u = relu(x@W1+b1), h = x@Ws+bs (both bf16) ----------------
__global__ __launch_bounds__(256) void embed_k(
    const float* __restrict__ x, const float* __restrict__ W1, const float* __restrict__ b1,
    const float* __restrict__ Ws, const float* __restrict__ bs,
    int* __restrict__ u2, int* __restrict__ h2, int Nn)
{
    int idx = blockIdx.x * 256 + threadIdx.x;
    if (idx >= Nn * 64) return;
    int n = idx >> 6, c = (idx & 63) * 2;
    float x0 = x[2*n], x1 = x[2*n+1];
    float u0 = fmaxf(fmaf(x1, W1[128+c],   fmaf(x0, W1[c],   b1[c])),   0.f);
    float u1 = fmaxf(fmaf(x1, W1[128+c+1], fmaf(x0, W1[c+1], b1[c+1])), 0.f);
    float h0 = fmaf(x1, Ws[128+c],   fmaf(x0, Ws[c],   bs[c]));
    float h1 = fmaf(x1, Ws[128+c+1], fmaf(x0, Ws[c+1], bs[c+1]));
    u2[idx] = pack2(u0, u1);
    h2[idx] = pack2(h0, h1);
}

// ------- bf16 MFMA GEMM: C = A[Nrows x K](bf16) @ Wt[nc][K](bf16) (+bias)(+R)(relu) -------
// 128x128 tile, 256 threads (4 waves), wave: 2 row-tiles x 8 col-tiles of 16x16x32 MFMA.
// BETA: add residual. CF32: C fp32 (reads C itself); else bf16 (reads Rres if given, else C).
template<int RELU, int BETA, int CF32>
__global__ __launch_bounds__(256) void gemm_mfma_k(
    const short* __restrict__ A, const short* __restrict__ Wt, int ldWt, int kofs,
    const float* __restrict__ bias, void* __restrict__ Cv, const short* __restrict__ Rres,
    int Nrows, int K, int ldC)
{
    __shared__ short As[128][40];  // pad 40 -> 80B row stride (16B aligned, 2-way banks only)
    __shared__ short Bs[128][40];
    const int row0 = blockIdx.x * 128;
    const int col0 = blockIdx.y * 128;
    const int t = threadIdx.x;
    const int w = t >> 6, lane = t & 63, q = lane >> 4, m = lane & 15;

    f32x4 acc[2][8];
    #pragma unroll
    for (int rb = 0; rb < 2; ++rb)
        #pragma unroll
        for (int cb = 0; cb < 8; ++cb)
            acc[rb][cb] = (f32x4){0.f, 0.f, 0.f, 0.f};

    for (int k0 = 0; k0 < K; k0 += 32) {
        #pragma unroll
        for (int it = 0; it < 2; ++it) {
            int ci = t + it * 256;
            int r = ci >> 2, kk = (ci & 3) * 8;
            int gr = row0 + r;
            int4 v = make_int4(0, 0, 0, 0);
            if (gr < Nrows) v = *(const int4*)(A + (size_t)gr * K + k0 + kk);
            *(int4*)&As[r][kk] = v;
        }
        #pragma unroll
        for (int it = 0; it < 2; ++it) {
            int ci = t + it * 256;
            int n = ci >> 2, kk = (ci & 3) * 8;
            *(int4*)&Bs[n][kk] = *(const int4*)(Wt + (size_t)(col0 + n) * ldWt + kofs + k0 + kk);
        }
        __syncthreads();
        bf16x8 af[2], bfr[8];
        af[0] = *(bf16x8*)&As[w * 32 + m][q * 8];
        af[1] = *(bf16x8*)&As[w * 32 + 16 + m][q * 8];
        #pragma unroll
        for (int cb = 0; cb < 8; ++cb)
            bfr[cb] = *(bf16x8*)&Bs[cb * 16 + m][q * 8];
        #pragma unroll
        for (int rb = 0; rb < 2; ++rb)
            #pragma unroll
            for (int cb = 0; cb < 8; ++cb)
                acc[rb][cb] = __builtin_amdgcn_mfma_f32_16x16x32_bf16(af[rb], bfr[cb], acc[rb][cb], 0, 0, 0);
        __syncthreads();
    }

    float* Cf = (float*)Cv;
    short* Cs = (short*)Cv;
    #pragma unroll
    for (int rb = 0; rb < 2; ++rb) {
        #pragma unroll
        for (int r = 0; r < 4; ++r) {
            int grow = row0 + w * 32 + rb * 16 + q * 4 + r;
            if (grow >= Nrows) continue;
            #pragma unroll
            for (int cb = 0; cb < 8; ++cb) {
                int gcol = col0 + cb * 16 + m;
                float v = acc[rb][cb][r];
                if (bias) v += bias[gcol];
                size_t off = (size_t)grow * ldC + gcol;
                if (BETA) {
                    if (CF32)      v += Cf[off];
                    else if (Rres) v += bf2f(Rres[off]);
                    else           v += bf2f(Cs[off]);
                }
                if (RELU) v = fmaxf(v, 0.f);
                if (CF32) Cf[off] = v; else Cs[off] = f2bf(v);
            }
        }
    }
}

// ------- dual GEMM (K=128, 128 cols each): y=0 -> Z=A@WtZ (bf16); y=1 -> D (+)= A@WtD slice (fp32) -------
__global__ __launch_bounds__(256) void gemm_dual_k(
    const short* __restrict__ A,
    const short* __restrict__ WtZ, short* __restrict__ Z,
    const short* __restrict__ WtD, int kofsD, const float* __restrict__ biasD,
    float* __restrict__ D, int betaD, int Nrows)
{
    const int isZ = (blockIdx.y == 0);
    if (isZ && WtZ == nullptr) return;
    const short* Wt = isZ ? WtZ : WtD;
    const int ldWt = isZ ? 128 : 640;
    const int kofs = isZ ? 0 : kofsD;

    __shared__ short As[128][40];
    __shared__ short Bs[128][40];
    const int row0 = blockIdx.x * 128;
    const int t = threadIdx.x;
    const int w = t >> 6, lane = t & 63, q = lane >> 4, m = lane & 15;

    f32x4 acc[2][8];
    #pragma unroll
    for (int rb = 0; rb < 2; ++rb)
        #pragma unroll
        for (int cb = 0; cb < 8; ++cb)
            acc[rb][cb] = (f32x4){0.f, 0.f, 0.f, 0.f};

    for (int k0 = 0; k0 < 128; k0 += 32) {
        #pragma unroll
        for (int it = 0; it < 2; ++it) {
            int ci = t + it * 256;
            int r = ci >> 2, kk = (ci & 3) * 8;
            int gr = row0 + r;
            int4 v = make_int4(0, 0, 0, 0);
            if (gr < Nrows) v = *(const int4*)(A + (size_t)gr * 128 + k0 + kk);
            *(int4*)&As[r][kk] = v;
        }
        #pragma unroll
        for (int it = 0; it < 2; ++it) {
            int ci = t + it * 256;
            int n = ci >> 2, kk = (ci & 3) * 8;
            *(int4*)&Bs[n][kk] = *(const int4*)(Wt + (size_t)n * ldWt + kofs + k0 + kk);
        }
        __syncthreads();
        bf16x8 af[2], bfr[8];
        af[0] = *(bf16x8*)&As[w * 32 + m][q * 8];
        af[1] = *(bf16x8*)&As[w * 32 + 16 + m][q * 8];
        #pragma unroll
        for (int cb = 0; cb < 8; ++cb)
            bfr[cb] = *(bf16x8*)&Bs[cb * 16 + m][q * 8];
        #pragma unroll
        for (int rb = 0; rb < 2; ++rb)
            #pragma unroll
            for (int cb = 0; cb < 8; ++cb)
                acc[rb][cb] = __builtin_amdgcn_mfma_f32_16x16x32_bf16(af[rb], bfr[cb], acc[rb][cb], 0, 0, 0);
        __syncthreads();
    }

    #pragma unroll
    for (int rb = 0; rb < 2; ++rb) {
        #pragma unroll
        for (int r = 0; r < 4; ++r) {
            int grow = row0 + w * 32 + rb * 16 + q * 4 + r;
            if (grow >= Nrows) continue;
            #pragma unroll
            for (int cb = 0; cb < 8; ++cb) {
                int gcol = cb * 16 + m;
                float v = acc[rb][cb][r];
                size_t off = (size_t)grow * 128 + gcol;
                if (isZ) {
                    Z[off] = f2bf(v);
                } else {
                    if (biasD) v += biasD[gcol];
                    if (betaD) v += D[off];
                    D[off] = v;
                }
            }
        }
    }
}

// ---------------- CSR build ----------------
__global__ void count_k(const int* __restrict__ dst, int* __restrict__ cnt, int E) {
    int e = blockIdx.x * 256 + threadIdx.x;
    if (e < E) atomicAdd(&cnt[dst[e]], 1);
}

__global__ __launch_bounds__(256) void scan_part_k(const int* __restrict__ cnt,
                                                   int* __restrict__ bsum, int Nn) {
    __shared__ int red[256];
    int base = blockIdx.x * 1024;
    int s = 0;
    for (int i = threadIdx.x; i < 1024; i += 256) {
        int g = base + i;
        if (g < Nn) s += cnt[g];
    }
    red[threadIdx.x] = s; __syncthreads();
    for (int off = 128; off; off >>= 1) {
        if ((int)threadIdx.x < off) red[threadIdx.x] += red[threadIdx.x + off];
        __syncthreads();
    }
    if (threadIdx.x == 0) bsum[blockIdx.x] = red[0];
}

__global__ __launch_bounds__(256) void scan_top_k(int* __restrict__ bsum, int nb) {
    __shared__ int buf[256];
    int v = ((int)threadIdx.x < nb) ? bsum[threadIdx.x] : 0;
    buf[threadIdx.x] = v; __syncthreads();
    for (int off = 1; off < 256; off <<= 1) {
        int tv = ((int)threadIdx.x >= off) ? buf[threadIdx.x - off] : 0;
        __syncthreads();
        buf[threadIdx.x] += tv;
        __syncthreads();
    }
    if ((int)threadIdx.x < nb) bsum[threadIdx.x] = buf[threadIdx.x] - v;
}

__global__ __launch_bounds__(256) void scan_fin_k(const int* __restrict__ cnt,
    const int* __restrict__ bsum, int* __restrict__ rowptr, int* __restrict__ wpos, int Nn)
{
    __shared__ int tsum[256];
    int base = blockIdx.x * 1024;
    int g0 = base + (int)threadIdx.x * 4;
    int v[4]; int s = 0;
    #pragma unroll
    for (int j = 0; j < 4; ++j) {
        int g = g0 + j;
        v[j] = (g < Nn) ? cnt[g] : 0;
        s += v[j];
    }
    tsum[threadIdx.x] = s; __syncthreads();
    for (int off = 1; off < 256; off <<= 1) {
        int tv = ((int)threadIdx.x >= off) ? tsum[threadIdx.x - off] : 0;
        __syncthreads();
        tsum[threadIdx.x] += tv;
        __syncthreads();
    }
    int run = bsum[blockIdx.x] + tsum[threadIdx.x] - s;
    #pragma unroll
    for (int j = 0; j < 4; ++j) {
        int g = g0 + j;
        if (g < Nn) { wpos[g] = run; rowptr[g + 1] = run + v[j]; }
        run += v[j];
    }
    if (blockIdx.x == 0 && threadIdx.x == 0) rowptr[0] = 0;
}

__global__ void scatter_k(const int* __restrict__ src, const int* __restrict__ dst,
                          int* __restrict__ wpos, int* __restrict__ esrc, int E) {
    int e = blockIdx.x * 256 + threadIdx.x;
    if (e < E) {
        int p = atomicAdd(&wpos[dst[e]], 1);
        esrc[p] = src[e];
    }
}

// ---------------- attention scalars el/er (z bf16) ----------------
__global__ __launch_bounds__(256) void elr_k(const short* __restrict__ z,
    const float* __restrict__ al, const float* __restrict__ ar,
    float* __restrict__ el, float* __restrict__ er, int Nn)
{
    int idx = blockIdx.x * 256 + threadIdx.x;  // n*16 + head
    if (idx >= Nn * 16) return;
    int hd = idx & 15;
    int4 zv = *(const int4*)(z + (size_t)idx * 8);
    float zf[8];
    zf[0] = bflo(zv.x); zf[1] = bfhi(zv.x);
    zf[2] = bflo(zv.y); zf[3] = bfhi(zv.y);
    zf[4] = bflo(zv.z); zf[5] = bfhi(zv.z);
    zf[6] = bflo(zv.w); zf[7] = bfhi(zv.w);
    float sl = 0.f, sr = 0.f;
    #pragma unroll
    for (int j = 0; j < 8; ++j) {
        sl = fmaf(zf[j], al[hd*8 + j], sl);
        sr = fmaf(zf[j], ar[hd*8 + j], sr);
    }
    el[idx] = sl; er[idx] = sr;
}

// ---------------- GAT aggregate: online softmax, one wave per node, unroll x2 ----------------
__global__ __launch_bounds__(256) void gat_k(
    const short* __restrict__ h, const short* __restrict__ z,
    const float* __restrict__ el, const float* __restrict__ er,
    const int* __restrict__ rowptr, const int* __restrict__ esrc,
    const float* __restrict__ gbias, short* __restrict__ t1, int Nn)
{
    int gw = (blockIdx.x * 256 + threadIdx.x) >> 6;
    if (gw >= Nn) return;
    int lane = threadIdx.x & 63;
    int c = lane * 2;
    int head = lane >> 2;
    float ern = er[gw*16 + head];
    int beg = rowptr[gw], end = rowptr[gw+1];
    float m = -3.0e38f, den = 0.f, a0 = 0.f, a1 = 0.f;
    int i = beg;
    for (; i + 1 < end; i += 2) {
        int s0 = esrc[i], s1 = esrc[i+1];
        float e0 = el[s0*16 + head] + ern;
        float e1 = el[s1*16 + head] + ern;
        int zz0 = *(const int*)(z + (size_t)s0*128 + c);
        int zz1 = *(const int*)(z + (size_t)s1*128 + c);
        e0 = (e0 > 0.f) ? e0 : 0.2f * e0;
        e1 = (e1 > 0.f) ? e1 : 0.2f * e1;
        float nm = fmaxf(m, fmaxf(e0, e1));
        float sc = __expf(m - nm);
        float w0 = __expf(e0 - nm);
        float w1 = __expf(e1 - nm);
        den = fmaf(den, sc, w0 + w1);
        a0  = fmaf(a0, sc, fmaf(w0, bflo(zz0), w1 * bflo(zz1)));
        a1  = fmaf(a1, sc, fmaf(w0, bfhi(zz0), w1 * bfhi(zz1)));
        m = nm;
    }
    if (i < end) {
        int s0 = esrc[i];
        float e0 = el[s0*16 + head] + ern;
        int zz0 = *(const int*)(z + (size_t)s0*128 + c);
        e0 = (e0 > 0.f) ? e0 : 0.2f * e0;
        float nm = fmaxf(m, e0);
        float sc = __expf(m - nm);
        float w0 = __expf(e0 - nm);
        den = fmaf(den, sc, w0);
        a0  = fmaf(a0, sc, w0 * bflo(zz0));
        a1  = fmaf(a1, sc, w0 * bfhi(zz0));
    }
    float inv = 1.f / den;
    size_t o = (size_t)gw*64 + lane;
    int hv = ((const int*)h)[o];
    float r0 = bflo(hv) + a0*inv + gbias[c];
    float r1 = bfhi(hv) + a1*inv + gbias[c+1];
    ((int*)t1)[o] = pack2(r0, r1);
}

// ---------------- BatchNorm (bf16 in, fp32 stats) ----------------
__global__ __launch_bounds__(256) void bn_stats_k(const short* __restrict__ xin,
    float* __restrict__ stats, int Nn)
{
    __shared__ float s0s[256], s1s[256], q0s[256], q1s[256];
    int pair = threadIdx.x & 63;
    int slot = threadIdx.x >> 6;
    float s0 = 0.f, s1 = 0.f, q0 = 0.f, q1 = 0.f;
    for (int r = blockIdx.x*4 + slot; r < Nn; r += gridDim.x*4) {
        int v = *(const int*)(xin + (size_t)r*128 + pair*2);
        float a = bflo(v), b = bfhi(v);
        s0 += a; s1 += b;
        q0 = fmaf(a, a, q0); q1 = fmaf(b, b, q1);
    }
    s0s[threadIdx.x] = s0; s1s[threadIdx.x] = s1;
    q0s[threadIdx.x] = q0; q1s[threadIdx.x] = q1;
    __syncthreads();
    if (slot == 0) {
        #pragma unroll
        for (int j = 1; j < 4; ++j) {
            s0 += s0s[pair + j*64]; s1 += s1s[pair + j*64];
            q0 += q0s[pair + j*64]; q1 += q1s[pair + j*64];
        }
        atomicAdd(&stats[pair*2],       s0);
        atomicAdd(&stats[pair*2+1],     s1);
        atomicAdd(&stats[128+pair*2],   q0);
        atomicAdd(&stats[128+pair*2+1], q1);
    }
}

__global__ __launch_bounds__(256) void bn_apply_k(const short* __restrict__ xin,
    const float* __restrict__ stats, const float* __restrict__ g, const float* __restrict__ b,
    short* __restrict__ hout, int Nn)
{
    int idx = blockIdx.x * 256 + threadIdx.x;
    if (idx >= Nn * 64) return;
    int c = (idx & 63) * 2;
    float invN = 1.f / (float)Nn;
    float mu0 = stats[c] * invN,   mu1 = stats[c+1] * invN;
    float v0 = stats[128+c] * invN - mu0*mu0;
    float v1 = stats[128+c+1] * invN - mu1*mu1;
    float sc0 = rsqrtf(v0 + 1e-5f) * g[c],   sc1 = rsqrtf(v1 + 1e-5f) * g[c+1];
    int v = ((const int*)xin)[idx];
    float y0 = (bflo(v) - mu0) * sc0 + b[c];
    float y1 = (bfhi(v) - mu1) * sc1 + b[c+1];
    ((int*)hout)[idx] = pack2(y0, y1);
}

// ---------------- decoder output ----------------
__global__ __launch_bounds__(256) void dec_out_k(const float* __restrict__ dacc,
    const float* __restrict__ W2, const float* __restrict__ b2,
    float* __restrict__ out, int Nn)
{
    int gw = (blockIdx.x * 256 + threadIdx.x) >> 6;
    if (gw >= Nn) return;
    int lane = threadIdx.x & 63;
    const float* row = dacc + (size_t)gw * 128;
    float v0 = fmaxf(row[lane],      0.f);
    float v1 = fmaxf(row[64 + lane], 0.f);
    float p = v0 * W2[lane] + v1 * W2[64 + lane];
    #pragma unroll
    for (int off = 32; off > 0; off >>= 1) p += __shfl_down(p, off);
    if (lane == 0) out[gw] = p + b2[0];
}

extern "C" void kernel_launch(void* const* d_in, const int* in_sizes, int n_in,
                              void* d_out, int out_size, void* d_ws, size_t ws_size,
                              hipStream_t stream)
{
    const float* x      = (const float*)d_in[0];
    const int*   src    = (const int*)  d_in[1];
    const int*   dst    = (const int*)  d_in[2];
    const float* emb_W1 = (const float*)d_in[3];
    const float* emb_b1 = (const float*)d_in[4];
    const float* emb_W2 = (const float*)d_in[5];
    const float* emb_b2 = (const float*)d_in[6];
    const float* emb_Ws = (const float*)d_in[7];
    const float* emb_bs = (const float*)d_in[8];
    const float* gat_W  = (const float*)d_in[9];
    const float* gat_al = (const float*)d_in[10];
    const float* gat_ar = (const float*)d_in[11];
    const float* gat_b  = (const float*)d_in[12];
    const float* bn1_g  = (const float*)d_in[13];
    const float* bn1_b  = (const float*)d_in[14];
    const float* ff_W1  = (const float*)d_in[15];
    const float* ff_b1  = (const float*)d_in[16];
    const float* ff_W2  = (const float*)d_in[17];
    const float* ff_b2  = (const float*)d_in[18];
    const float* bn2_g  = (const float*)d_in[19];
    const float* bn2_b  = (const float*)d_in[20];
    const float* dec_W1 = (const float*)d_in[21];
    const float* dec_b1 = (const float*)d_in[22];
    const float* dec_W2 = (const float*)d_in[23];
    const float* dec_b2 = (const float*)d_in[24];
    float* out = (float*)d_out;
    (void)n_in; (void)out_size;

    const int N = in_sizes[0] / 2;
    const int E = in_sizes[1];

    // ---- workspace ----
    char* p = (char*)d_ws;
    size_t used = 0;
    auto carve = [&](size_t bytes) {
        char* r = p; size_t a = (bytes + 255) & ~(size_t)255;
        p += a; used += a; return r;
    };
    const size_t nb128 = (size_t)N * 128 * 4;
    short* h    = (short*)carve(nb128 / 2);
    short* t1   = (short*)carve(nb128 / 2);
    float* dacc = (float*)carve(nb128);
    char*  big  = (char*)carve(nb128);     // u / (z | el | er) / ffh  (bf16 phases)
    int*   cnt    = (int*)carve((size_t)N * 4);
    float* stats8 = (float*)carve(8 * 256 * 4);   // adjacent to cnt: zeroed together
    int*   rowptr = (int*)carve((size_t)(N + 1) * 4);
    int*   wpos   = (int*)carve((size_t)N * 4);
    int*   esrc   = (int*)carve((size_t)E * 4);
    int*   bsum   = (int*)carve(256 * 4);
    short* emb_W2t = (short*)carve((size_t)128 * 128 * 2);
    short* gat_Wt  = (short*)carve((size_t)4 * 128 * 128 * 2);
    short* ff_W1t  = (short*)carve((size_t)4 * 128 * 256 * 2);
    short* ff_W2t  = (short*)carve((size_t)4 * 256 * 128 * 2);
    short* dec_W1t = (short*)carve((size_t)640 * 128 * 2);
    if (used > ws_size) return;

    short* u   = (short*)big;
    short* z   = (short*)big;
    float* el  = (float*)(big + (size_t)N * 128 * 2);
    float* er  = el + (size_t)N * 16;
    short* ffh = (short*)big;

    dim3 b256(256);
    int ecb  = (E + 255) / 256;
    int nel2 = (N * 64 + 255) / 256;
    int gx   = (N + 127) / 128;
    int nwv  = (N + 3) / 4;
    int nb   = (N + 1023) / 1024;

    // ---- weight convert + transpose ----
    wconv_k<<<dim3(64, 1), b256, 0, stream>>>(emb_W2, emb_W2t, 128, 128);
    wconv_k<<<dim3(64, 4), b256, 0, stream>>>(gat_W,  gat_Wt,  128, 128);
    wconv_k<<<dim3(128, 4), b256, 0, stream>>>(ff_W1, ff_W1t,  128, 256);
    wconv_k<<<dim3(128, 4), b256, 0, stream>>>(ff_W2, ff_W2t,  256, 128);
    wconv_k<<<dim3(320, 1), b256, 0, stream>>>(dec_W1, dec_W1t, 640, 128);

    // ---- zero cnt + all 8 BN stats buffers in one launch (contiguous carve region) ----
    {
        int ztot = (int)(((char*)(stats8 + 8*256) - (char*)cnt) / 4);
        zero_i32_k<<<(ztot + 255) / 256, b256, 0, stream>>>(cnt, ztot);
    }

    // ---- CSR build ----
    count_k<<<ecb, b256, 0, stream>>>(dst, cnt, E);
    scan_part_k<<<nb, b256, 0, stream>>>(cnt, bsum, N);
    scan_top_k<<<1, b256, 0, stream>>>(bsum, nb);
    scan_fin_k<<<nb, b256, 0, stream>>>(cnt, bsum, rowptr, wpos, N);
    scatter_k<<<ecb, b256, 0, stream>>>(src, dst, wpos, esrc, E);

    // ---- embed ----
    embed_k<<<nel2, b256, 0, stream>>>(x, emb_W1, emb_b1, emb_Ws, emb_bs, (int*)u, (int*)h, N);
    gemm_mfma_k<0,1,0><<<dim3(gx,1), b256, 0, stream>>>(u, emb_W2t, 128, 0, emb_b2, h, nullptr, N, 128, 128);
    // xs[0]=h: dacc = h@dec[0]+b ; z = h@gatW[0]
    gemm_dual_k<<<dim3(gx,2), b256, 0, stream>>>(h, gat_Wt, z, dec_W1t, 0, dec_b1, dacc, 0, N);

    for (int l = 0; l < 4; ++l) {
        float* st1 = stats8 + (size_t)(l*2)   * 256;
        float* st2 = stats8 + (size_t)(l*2+1) * 256;
        elr_k<<<(N*16 + 255)/256, b256, 0, stream>>>(z, gat_al + l*128, gat_ar + l*128, el, er, N);
        gat_k<<<nwv, b256, 0, stream>>>(h, z, el, er, rowptr, esrc, gat_b + l*128, t1, N);
        bn_stats_k<<<400, b256, 0, stream>>>(t1, st1, N);
        bn_apply_k<<<nel2, b256, 0, stream>>>(t1, st1, bn1_g + l*128, bn1_b + l*128, h, N);
        // FF: ffh = relu(h@W1+b1); t1 = h + ffh@W2 + b2  (residual h via Rres)
        gemm_mfma_k<1,0,0><<<dim3(gx,2), b256, 0, stream>>>(h, ff_W1t + (size_t)l*128*256, 128, 0, ff_b1 + l*256, ffh, nullptr, N, 128, 256);
        gemm_mfma_k<0,1,0><<<dim3(gx,1), b256, 0, stream>>>(ffh, ff_W2t + (size_t)l*256*128, 256, 0, ff_b2 + l*128, t1, h, N, 256, 128);
        bn_stats_k<<<400, b256, 0, stream>>>(t1, st2, N);
        bn_apply_k<<<nel2, b256, 0, stream>>>(t1, st2, bn2_g + l*128, bn2_b + l*128, h, N);
        // xs[l+1]=h: dacc += h@dec[l+1] ; z = h@gatW[l+1] (skip z for l==3)
        const short* nextW = (l < 3) ? (gat_Wt + (size_t)(l+1)*128*128) : nullptr;
        gemm_dual_k<<<dim3(gx,2), b256, 0, stream>>>(h, nextW, z, dec_W1t, (l+1)*128, nullptr, dacc, 1, N);
    }

    dec_out_k<<<nwv, b256, 0, stream>>>(dacc, dec_W2, dec_b2, out, N);
}

// Round 6
// 1481.741 us; speedup vs baseline: 1.8711x; 1.0933x over previous
//
#include <hip/hip_runtime.h>
#include <math.h>

typedef __attribute__((ext_vector_type(8))) short bf16x8;
typedef __attribute__((ext_vector_type(4))) float f32x4;

static __device__ __forceinline__ short f2bf(float f) {
    unsigned u = __float_as_uint(f);
    unsigned r = (u + 0x7fffu + ((u >> 16) & 1u)) >> 16;
    return (short)r;
}
static __device__ __forceinline__ float bf2f(short s) {
    return __uint_as_float(((unsigned)(unsigned short)s) << 16);
}
static __device__ __forceinline__ float bflo(int v) { return bf2f((short)(v & 0xffff)); }
static __device__ __forceinline__ float bfhi(int v) { return bf2f((short)(((unsigned)v) >> 16)); }
static __device__ __forceinline__ int pack2(float a, float b) {
    return (int)(((unsigned)(unsigned short)f2bf(b) << 16) | (unsigned)(unsigned short)f2bf(a));
}

// ---------------- zero fill ----------------
__global__ void zero_i32_k(int* __restrict__ p, int n) {
    int i = blockIdx.x * 256 + threadIdx.x;
    if (i < n) p[i] = 0;
}

// ---------------- weight convert+transpose: W[K x Nc] fp32 -> Wt[Nc x K] bf16 ----------------
__global__ __launch_bounds__(256) void wconv_k(const float* __restrict__ W, short* __restrict__ Wt,
                                               int K, int Nc) {
    int slice = blockIdx.y;
    const float* src = W + (size_t)slice * K * Nc;
    short* dst = Wt + (size_t)slice * K * Nc;
    int idx = blockIdx.x * 256 + threadIdx.x;
    if (idx >= K * Nc) return;
    int k = idx / Nc, n = idx - k * Nc;
    dst[(size_t)n * K + k] = f2bf(src[idx]);
}

// ---------------- embed: u = relu(x@W1+b1), h = x@Ws+bs (both bf16) ----------------
__global__ __launch_bounds__(256) void embed_k(
    const float* __restrict__ x, const float* __restrict__ W1, const float* __restrict__ b1,
    const float* __restrict__ Ws, const float* __restrict__ bs,
    int* __restrict__ u2, int* __restrict__ h2, int Nn)
{
    int idx = blockIdx.x * 256 + threadIdx.x;
    if (idx >= Nn * 64) return;
    int n = idx >> 6, c = (idx & 63) * 2;
    float x0 = x[2*n], x1 = x[2*n+1];
    float u0 = fmaxf(fmaf(x1, W1[128+c],   fmaf(x0, W1[c],   b1[c])),   0.f);
    float u1 = fmaxf(fmaf(x1, W1[128+c+1], fmaf(x0, W1[c+1], b1[c+1])), 0.f);
    float h0 = fmaf(x1, Ws[128+c],   fmaf(x0, Ws[c],   bs[c]));
    float h1 = fmaf(x1, Ws[128+c+1], fmaf(x0, Ws[c+1], bs[c+1]));
    u2[idx] = pack2(u0, u1);
    h2[idx] = pack2(h0, h1);
}

// ------- bf16 MFMA GEMM v2: B in LDS (per 128-k chunk), A fragments direct from global -------
// K = NK*128, A given as NK chunk base pointers (row stride Astr shorts).
// C bf16 [Nrows x ldC]; BETA: += (Rres ? Rres : C); RELU on output.
template<int NK, int RELU, int BETA>
__global__ __launch_bounds__(256) void gemm2_k(
    const short* __restrict__ A0, const short* __restrict__ A1,
    const short* __restrict__ A2, const short* __restrict__ A3,
    const short* __restrict__ A4, int Astr,
    const short* __restrict__ Wt, int ldWt,
    const float* __restrict__ bias, short* __restrict__ C, const short* __restrict__ Rres,
    int Nrows, int ldC)
{
    __shared__ short Bs[128][136];   // 272B row stride = 17*16B: 16B-aligned, 2-way banks (free)
    const int row0 = blockIdx.x * 128;
    const int col0 = blockIdx.y * 128;
    const int t = threadIdx.x;
    const int w = t >> 6, lane = t & 63, q = lane >> 4, m = lane & 15;

    f32x4 acc[2][8];
    #pragma unroll
    for (int rb = 0; rb < 2; ++rb)
        #pragma unroll
        for (int cb = 0; cb < 8; ++cb)
            acc[rb][cb] = (f32x4){0.f, 0.f, 0.f, 0.f};

    const short* Asrc[5] = {A0, A1, A2, A3, A4};
    int rr0 = row0 + w*32 + m;      if (rr0 > Nrows - 1) rr0 = Nrows - 1;
    int rr1 = row0 + w*32 + 16 + m; if (rr1 > Nrows - 1) rr1 = Nrows - 1;

    #pragma unroll
    for (int kh = 0; kh < NK; ++kh) {
        if (kh) __syncthreads();
        // stage B chunk: 128 cols x 128 k bf16 = 32KB; 8 x int4 per thread, all independent
        #pragma unroll
        for (int it = 0; it < 8; ++it) {
            int ci = t + it * 256;
            int r = ci >> 4, j = (ci & 15) * 8;
            *(int4*)&Bs[r][j] = *(const int4*)(Wt + (size_t)(col0 + r) * ldWt + kh * 128 + j);
        }
        const short* pa0 = Asrc[kh] + (size_t)rr0 * Astr + q * 8;
        const short* pa1 = Asrc[kh] + (size_t)rr1 * Astr + q * 8;
        __syncthreads();
        #pragma unroll
        for (int ks = 0; ks < 4; ++ks) {
            bf16x8 af0 = *(const bf16x8*)(pa0 + ks * 32);
            bf16x8 af1 = *(const bf16x8*)(pa1 + ks * 32);
            bf16x8 bfr[8];
            #pragma unroll
            for (int cb = 0; cb < 8; ++cb)
                bfr[cb] = *(const bf16x8*)&Bs[cb * 16 + m][ks * 32 + q * 8];
            #pragma unroll
            for (int cb = 0; cb < 8; ++cb) {
                acc[0][cb] = __builtin_amdgcn_mfma_f32_16x16x32_bf16(af0, bfr[cb], acc[0][cb], 0, 0, 0);
                acc[1][cb] = __builtin_amdgcn_mfma_f32_16x16x32_bf16(af1, bfr[cb], acc[1][cb], 0, 0, 0);
            }
        }
    }

    const short* Rd = Rres ? Rres : C;
    #pragma unroll
    for (int rb = 0; rb < 2; ++rb) {
        #pragma unroll
        for (int r = 0; r < 4; ++r) {
            int grow = row0 + w * 32 + rb * 16 + q * 4 + r;
            if (grow >= Nrows) continue;
            #pragma unroll
            for (int cb = 0; cb < 8; ++cb) {
                int gcol = col0 + cb * 16 + m;
                float v = acc[rb][cb][r];
                if (bias) v += bias[gcol];
                size_t off = (size_t)grow * ldC + gcol;
                if (BETA) v += bf2f(Rd[off]);
                if (RELU) v = fmaxf(v, 0.f);
                C[off] = f2bf(v);
            }
        }
    }
}

// ---------------- CSR build ----------------
__global__ void count_k(const int* __restrict__ dst, int* __restrict__ cnt, int E) {
    int e = blockIdx.x * 256 + threadIdx.x;
    if (e < E) atomicAdd(&cnt[dst[e]], 1);
}

__global__ __launch_bounds__(256) void scan_part_k(const int* __restrict__ cnt,
                                                   int* __restrict__ bsum, int Nn) {
    __shared__ int red[256];
    int base = blockIdx.x * 1024;
    int s = 0;
    for (int i = threadIdx.x; i < 1024; i += 256) {
        int g = base + i;
        if (g < Nn) s += cnt[g];
    }
    red[threadIdx.x] = s; __syncthreads();
    for (int off = 128; off; off >>= 1) {
        if ((int)threadIdx.x < off) red[threadIdx.x] += red[threadIdx.x + off];
        __syncthreads();
    }
    if (threadIdx.x == 0) bsum[blockIdx.x] = red[0];
}

__global__ __launch_bounds__(256) void scan_top_k(int* __restrict__ bsum, int nb) {
    __shared__ int buf[256];
    int v = ((int)threadIdx.x < nb) ? bsum[threadIdx.x] : 0;
    buf[threadIdx.x] = v; __syncthreads();
    for (int off = 1; off < 256; off <<= 1) {
        int tv = ((int)threadIdx.x >= off) ? buf[threadIdx.x - off] : 0;
        __syncthreads();
        buf[threadIdx.x] += tv;
        __syncthreads();
    }
    if ((int)threadIdx.x < nb) bsum[threadIdx.x] = buf[threadIdx.x] - v;
}

__global__ __launch_bounds__(256) void scan_fin_k(const int* __restrict__ cnt,
    const int* __restrict__ bsum, int* __restrict__ rowptr, int* __restrict__ wpos, int Nn)
{
    __shared__ int tsum[256];
    int base = blockIdx.x * 1024;
    int g0 = base + (int)threadIdx.x * 4;
    int v[4]; int s = 0;
    #pragma unroll
    for (int j = 0; j < 4; ++j) {
        int g = g0 + j;
        v[j] = (g < Nn) ? cnt[g] : 0;
        s += v[j];
    }
    tsum[threadIdx.x] = s; __syncthreads();
    for (int off = 1; off < 256; off <<= 1) {
        int tv = ((int)threadIdx.x >= off) ? tsum[threadIdx.x - off] : 0;
        __syncthreads();
        tsum[threadIdx.x] += tv;
        __syncthreads();
    }
    int run = bsum[blockIdx.x] + tsum[threadIdx.x] - s;
    #pragma unroll
    for (int j = 0; j < 4; ++j) {
        int g = g0 + j;
        if (g < Nn) { wpos[g] = run; rowptr[g + 1] = run + v[j]; }
        run += v[j];
    }
    if (blockIdx.x == 0 && threadIdx.x == 0) rowptr[0] = 0;
}

__global__ void scatter_k(const int* __restrict__ src, const int* __restrict__ dst,
                          int* __restrict__ wpos, int* __restrict__ esrc, int E) {
    int e = blockIdx.x * 256 + threadIdx.x;
    if (e < E) {
        int p = atomicAdd(&wpos[dst[e]], 1);
        esrc[p] = src[e];
    }
}

// ---------------- attention scalars el/er (z bf16) ----------------
__global__ __launch_bounds__(256) void elr_k(const short* __restrict__ z,
    const float* __restrict__ al, const float* __restrict__ ar,
    float* __restrict__ el, float* __restrict__ er, int Nn)
{
    int idx = blockIdx.x * 256 + threadIdx.x;  // n*16 + head
    if (idx >= Nn * 16) return;
    int hd = idx & 15;
    int4 zv = *(const int4*)(z + (size_t)idx * 8);
    float zf[8];
    zf[0] = bflo(zv.x); zf[1] = bfhi(zv.x);
    zf[2] = bflo(zv.y); zf[3] = bfhi(zv.y);
    zf[4] = bflo(zv.z); zf[5] = bfhi(zv.z);
    zf[6] = bflo(zv.w); zf[7] = bfhi(zv.w);
    float sl = 0.f, sr = 0.f;
    #pragma unroll
    for (int j = 0; j < 8; ++j) {
        sl = fmaf(zf[j], al[hd*8 + j], sl);
        sr = fmaf(zf[j], ar[hd*8 + j], sr);
    }
    el[idx] = sl; er[idx] = sr;
}

// ---------------- GAT aggregate: online softmax, one wave per node, unroll x2 ----------------
__global__ __launch_bounds__(256) void gat_k(
    const short* __restrict__ h, const short* __restrict__ z,
    const float* __restrict__ el, const float* __restrict__ er,
    const int* __restrict__ rowptr, const int* __restrict__ esrc,
    const float* __restrict__ gbias, short* __restrict__ t1, int Nn)
{
    int gw = (blockIdx.x * 256 + threadIdx.x) >> 6;
    if (gw >= Nn) return;
    int lane = threadIdx.x & 63;
    int c = lane * 2;
    int head = lane >> 2;
    float ern = er[gw*16 + head];
    int beg = rowptr[gw], end = rowptr[gw+1];
    float m = -3.0e38f, den = 0.f, a0 = 0.f, a1 = 0.f;
    int i = beg;
    for (; i + 1 < end; i += 2) {
        int s0 = esrc[i], s1 = esrc[i+1];
        float e0 = el[s0*16 + head] + ern;
        float e1 = el[s1*16 + head] + ern;
        int zz0 = *(const int*)(z + (size_t)s0*128 + c);
        int zz1 = *(const int*)(z + (size_t)s1*128 + c);
        e0 = (e0 > 0.f) ? e0 : 0.2f * e0;
        e1 = (e1 > 0.f) ? e1 : 0.2f * e1;
        float nm = fmaxf(m, fmaxf(e0, e1));
        float sc = __expf(m - nm);
        float w0 = __expf(e0 - nm);
        float w1 = __expf(e1 - nm);
        den = fmaf(den, sc, w0 + w1);
        a0  = fmaf(a0, sc, fmaf(w0, bflo(zz0), w1 * bflo(zz1)));
        a1  = fmaf(a1, sc, fmaf(w0, bfhi(zz0), w1 * bfhi(zz1)));
        m = nm;
    }
    if (i < end) {
        int s0 = esrc[i];
        float e0 = el[s0*16 + head] + ern;
        int zz0 = *(const int*)(z + (size_t)s0*128 + c);
        e0 = (e0 > 0.f) ? e0 : 0.2f * e0;
        float nm = fmaxf(m, e0);
        float sc = __expf(m - nm);
        float w0 = __expf(e0 - nm);
        den = fmaf(den, sc, w0);
        a0  = fmaf(a0, sc, w0 * bflo(zz0));
        a1  = fmaf(a1, sc, w0 * bfhi(zz0));
    }
    float inv = 1.f / den;
    size_t o = (size_t)gw*64 + lane;
    int hv = ((const int*)h)[o];
    float r0 = bflo(hv) + a0*inv + gbias[c];
    float r1 = bfhi(hv) + a1*inv + gbias[c+1];
    ((int*)t1)[o] = pack2(r0, r1);
}

// ---------------- BatchNorm (bf16 in, fp32 stats) ----------------
__global__ __launch_bounds__(256) void bn_stats_k(const short* __restrict__ xin,
    float* __restrict__ stats, int Nn)
{
    __shared__ float s0s[256], s1s[256], q0s[256], q1s[256];
    int pair = threadIdx.x & 63;
    int slot = threadIdx.x >> 6;
    float s0 = 0.f, s1 = 0.f, q0 = 0.f, q1 = 0.f;
    for (int r = blockIdx.x*4 + slot; r < Nn; r += gridDim.x*4) {
        int v = *(const int*)(xin + (size_t)r*128 + pair*2);
        float a = bflo(v), b = bfhi(v);
        s0 += a; s1 += b;
        q0 = fmaf(a, a, q0); q1 = fmaf(b, b, q1);
    }
    s0s[threadIdx.x] = s0; s1s[threadIdx.x] = s1;
    q0s[threadIdx.x] = q0; q1s[threadIdx.x] = q1;
    __syncthreads();
    if (slot == 0) {
        #pragma unroll
        for (int j = 1; j < 4; ++j) {
            s0 += s0s[pair + j*64]; s1 += s1s[pair + j*64];
            q0 += q0s[pair + j*64]; q1 += q1s[pair + j*64];
        }
        atomicAdd(&stats[pair*2],       s0);
        atomicAdd(&stats[pair*2+1],     s1);
        atomicAdd(&stats[128+pair*2],   q0);
        atomicAdd(&stats[128+pair*2+1], q1);
    }
}

__global__ __launch_bounds__(256) void bn_apply_k(const short* __restrict__ xin,
    const float* __restrict__ stats, const float* __restrict__ g, const float* __restrict__ b,
    short* __restrict__ hout, int Nn)
{
    int idx = blockIdx.x * 256 + threadIdx.x;
    if (idx >= Nn * 64) return;
    int c = (idx & 63) * 2;
    float invN = 1.f / (float)Nn;
    float mu0 = stats[c] * invN,   mu1 = stats[c+1] * invN;
    float v0 = stats[128+c] * invN - mu0*mu0;
    float v1 = stats[128+c+1] * invN - mu1*mu1;
    float sc0 = rsqrtf(v0 + 1e-5f) * g[c],   sc1 = rsqrtf(v1 + 1e-5f) * g[c+1];
    int v = ((const int*)xin)[idx];
    float y0 = (bflo(v) - mu0) * sc0 + b[c];
    float y1 = (bfhi(v) - mu1) * sc1 + b[c+1];
    ((int*)hout)[idx] = pack2(y0, y1);
}

// ---------------- decoder output: out[n] = udec[n,:] . W2 + b2 (udec bf16, relu pre-applied) ----------------
__global__ __launch_bounds__(256) void dec_out_k(const short* __restrict__ udec,
    const float* __restrict__ W2, const float* __restrict__ b2,
    float* __restrict__ out, int Nn)
{
    int gw = (blockIdx.x * 256 + threadIdx.x) >> 6;
    if (gw >= Nn) return;
    int lane = threadIdx.x & 63;
    int v = ((const int*)(udec + (size_t)gw * 128))[lane];
    float p = bflo(v) * W2[lane*2] + bfhi(v) * W2[lane*2 + 1];
    #pragma unroll
    for (int off = 32; off > 0; off >>= 1) p += __shfl_down(p, off);
    if (lane == 0) out[gw] = p + b2[0];
}

extern "C" void kernel_launch(void* const* d_in, const int* in_sizes, int n_in,
                              void* d_out, int out_size, void* d_ws, size_t ws_size,
                              hipStream_t stream)
{
    const float* x      = (const float*)d_in[0];
    const int*   src    = (const int*)  d_in[1];
    const int*   dst    = (const int*)  d_in[2];
    const float* emb_W1 = (const float*)d_in[3];
    const float* emb_b1 = (const float*)d_in[4];
    const float* emb_W2 = (const float*)d_in[5];
    const float* emb_b2 = (const float*)d_in[6];
    const float* emb_Ws = (const float*)d_in[7];
    const float* emb_bs = (const float*)d_in[8];
    const float* gat_W  = (const float*)d_in[9];
    const float* gat_al = (const float*)d_in[10];
    const float* gat_ar = (const float*)d_in[11];
    const float* gat_b  = (const float*)d_in[12];
    const float* bn1_g  = (const float*)d_in[13];
    const float* bn1_b  = (const float*)d_in[14];
    const float* ff_W1  = (const float*)d_in[15];
    const float* ff_b1  = (const float*)d_in[16];
    const float* ff_W2  = (const float*)d_in[17];
    const float* ff_b2  = (const float*)d_in[18];
    const float* bn2_g  = (const float*)d_in[19];
    const float* bn2_b  = (const float*)d_in[20];
    const float* dec_W1 = (const float*)d_in[21];
    const float* dec_b1 = (const float*)d_in[22];
    const float* dec_W2 = (const float*)d_in[23];
    const float* dec_b2 = (const float*)d_in[24];
    float* out = (float*)d_out;
    (void)n_in; (void)out_size;

    const int N = in_sizes[0] / 2;
    const int E = in_sizes[1];

    // ---- workspace (~235 MB) ----
    char* p = (char*)d_ws;
    size_t used = 0;
    auto carve = [&](size_t bytes) {
        char* r = p; size_t a = (bytes + 255) & ~(size_t)255;
        p += a; used += a; return r;
    };
    const size_t nbH = (size_t)N * 128 * 2;   // one bf16 feature map
    short* xs[5];
    for (int i = 0; i < 5; ++i) xs[i] = (short*)carve(nbH);
    short* hmid = (short*)carve(nbH);
    short* t1   = (short*)carve(nbH);
    char*  big  = (char*)carve(2 * nbH);      // u / (z | el | er) / ffh / udec
    int*   cnt    = (int*)carve((size_t)N * 4);
    float* stats8 = (float*)carve(8 * 256 * 4);   // adjacent to cnt: zeroed together
    int*   rowptr = (int*)carve((size_t)(N + 1) * 4);
    int*   wpos   = (int*)carve((size_t)N * 4);
    int*   esrc   = (int*)carve((size_t)E * 4);
    int*   bsum   = (int*)carve(256 * 4);
    short* emb_W2t = (short*)carve((size_t)128 * 128 * 2);
    short* gat_Wt  = (short*)carve((size_t)4 * 128 * 128 * 2);
    short* ff_W1t  = (short*)carve((size_t)4 * 128 * 256 * 2);
    short* ff_W2t  = (short*)carve((size_t)4 * 256 * 128 * 2);
    short* dec_W1t = (short*)carve((size_t)640 * 128 * 2);
    if (used > ws_size) return;

    short* u    = (short*)big;                    // embed phase
    short* z    = (short*)big;                    // GAT phase
    float* el   = (float*)(big + nbH);            // GAT phase
    float* er   = el + (size_t)N * 16;
    short* ffh  = (short*)big;                    // FF phase (N x 256)
    short* udec = (short*)big;                    // decoder phase

    dim3 b256(256);
    int ecb  = (E + 255) / 256;
    int nel2 = (N * 64 + 255) / 256;
    int gx   = (N + 127) / 128;
    int nwv  = (N + 3) / 4;
    int nb   = (N + 1023) / 1024;

    // ---- weight convert + transpose ----
    wconv_k<<<dim3(64, 1), b256, 0, stream>>>(emb_W2, emb_W2t, 128, 128);
    wconv_k<<<dim3(64, 4), b256, 0, stream>>>(gat_W,  gat_Wt,  128, 128);
    wconv_k<<<dim3(128, 4), b256, 0, stream>>>(ff_W1, ff_W1t,  128, 256);
    wconv_k<<<dim3(128, 4), b256, 0, stream>>>(ff_W2, ff_W2t,  256, 128);
    wconv_k<<<dim3(320, 1), b256, 0, stream>>>(dec_W1, dec_W1t, 640, 128);

    // ---- zero cnt + 8 BN stats buffers (contiguous) ----
    {
        int ztot = (int)(((char*)(stats8 + 8*256) - (char*)cnt) / 4);
        zero_i32_k<<<(ztot + 255) / 256, b256, 0, stream>>>(cnt, ztot);
    }

    // ---- CSR build ----
    count_k<<<ecb, b256, 0, stream>>>(dst, cnt, E);
    scan_part_k<<<nb, b256, 0, stream>>>(cnt, bsum, N);
    scan_top_k<<<1, b256, 0, stream>>>(bsum, nb);
    scan_fin_k<<<nb, b256, 0, stream>>>(cnt, bsum, rowptr, wpos, N);
    scatter_k<<<ecb, b256, 0, stream>>>(src, dst, wpos, esrc, E);

    // ---- embed: xs0 = relu(x@W1+b1)@W2 + b2 + (x@Ws+bs) ----
    embed_k<<<nel2, b256, 0, stream>>>(x, emb_W1, emb_b1, emb_Ws, emb_bs, (int*)u, (int*)xs[0], N);
    gemm2_k<1,0,1><<<dim3(gx,1), b256, 0, stream>>>(u,u,u,u,u, 128, emb_W2t, 128,
                                                    emb_b2, xs[0], nullptr, N, 128);

    for (int l = 0; l < 4; ++l) {
        float* st1 = stats8 + (size_t)(l*2)   * 256;
        float* st2 = stats8 + (size_t)(l*2+1) * 256;
        short* hl = xs[l];
        // z = xs[l] @ gatW[l]
        gemm2_k<1,0,0><<<dim3(gx,1), b256, 0, stream>>>(hl,hl,hl,hl,hl, 128,
            gat_Wt + (size_t)l*128*128, 128, nullptr, z, nullptr, N, 128);
        elr_k<<<(N*16 + 255)/256, b256, 0, stream>>>(z, gat_al + l*128, gat_ar + l*128, el, er, N);
        gat_k<<<nwv, b256, 0, stream>>>(hl, z, el, er, rowptr, esrc, gat_b + l*128, t1, N);
        bn_stats_k<<<400, b256, 0, stream>>>(t1, st1, N);
        bn_apply_k<<<nel2, b256, 0, stream>>>(t1, st1, bn1_g + l*128, bn1_b + l*128, hmid, N);
        // FF: ffh = relu(hmid@W1+b1); t1 = hmid + ffh@W2 + b2
        gemm2_k<1,1,0><<<dim3(gx,2), b256, 0, stream>>>(hmid,hmid,hmid,hmid,hmid, 128,
            ff_W1t + (size_t)l*128*256, 128, ff_b1 + l*256, ffh, nullptr, N, 256);
        gemm2_k<2,0,1><<<dim3(gx,1), b256, 0, stream>>>(ffh, ffh + 128, ffh, ffh, ffh, 256,
            ff_W2t + (size_t)l*256*128, 256, ff_b2 + l*128, t1, hmid, N, 128);
        bn_stats_k<<<400, b256, 0, stream>>>(t1, st2, N);
        bn_apply_k<<<nel2, b256, 0, stream>>>(t1, st2, bn2_g + l*128, bn2_b + l*128, xs[l+1], N);
    }

    // ---- decoder: udec = relu(concat(xs) @ dec_W1 + b1)  (virtual concat, K=640) ----
    gemm2_k<5,1,0><<<dim3(gx,1), b256, 0, stream>>>(xs[0], xs[1], xs[2], xs[3], xs[4], 128,
        dec_W1t, 640, dec_b1, udec, nullptr, N, 128);
    dec_out_k<<<nwv, b256, 0, stream>>>(udec, dec_W2, dec_b2, out, N);
}

// Round 7
// 1439.079 us; speedup vs baseline: 1.9265x; 1.0296x over previous
//
#include <hip/hip_runtime.h>
#include <math.h>

typedef __attribute__((ext_vector_type(8))) short bf16x8;
typedef __attribute__((ext_vector_type(4))) float f32x4;

static __device__ __forceinline__ short f2bf(float f) {
    unsigned u = __float_as_uint(f);
    unsigned r = (u + 0x7fffu + ((u >> 16) & 1u)) >> 16;
    return (short)r;
}
static __device__ __forceinline__ float bf2f(short s) {
    return __uint_as_float(((unsigned)(unsigned short)s) << 16);
}
static __device__ __forceinline__ float bflo(int v) { return bf2f((short)(v & 0xffff)); }
static __device__ __forceinline__ float bfhi(int v) { return bf2f((short)(((unsigned)v) >> 16)); }
static __device__ __forceinline__ int pack2(float a, float b) {
    return (int)(((unsigned)(unsigned short)f2bf(b) << 16) | (unsigned)(unsigned short)f2bf(a));
}

// ---------------- zero fill ----------------
__global__ void zero_i32_k(int* __restrict__ p, int n) {
    int i = blockIdx.x * 256 + threadIdx.x;
    if (i < n) p[i] = 0;
}

// ---------------- weight convert+transpose: W[K x Nc] fp32 -> Wt[Nc x K] bf16 ----------------
__global__ __launch_bounds__(256) void wconv_k(const float* __restrict__ W, short* __restrict__ Wt,
                                               int K, int Nc) {
    int slice = blockIdx.y;
    const float* src = W + (size_t)slice * K * Nc;
    short* dst = Wt + (size_t)slice * K * Nc;
    int idx = blockIdx.x * 256 + threadIdx.x;
    if (idx >= K * Nc) return;
    int k = idx / Nc, n = idx - k * Nc;
    dst[(size_t)n * K + k] = f2bf(src[idx]);
}

// ---------------- embed: u = relu(x@W1+b1), h = x@Ws+bs (both bf16) ----------------
__global__ __launch_bounds__(256) void embed_k(
    const float* __restrict__ x, const float* __restrict__ W1, const float* __restrict__ b1,
    const float* __restrict__ Ws, const float* __restrict__ bs,
    int* __restrict__ u2, int* __restrict__ h2, int Nn)
{
    int idx = blockIdx.x * 256 + threadIdx.x;
    if (idx >= Nn * 64) return;
    int n = idx >> 6, c = (idx & 63) * 2;
    float x0 = x[2*n], x1 = x[2*n+1];
    float u0 = fmaxf(fmaf(x1, W1[128+c],   fmaf(x0, W1[c],   b1[c])),   0.f);
    float u1 = fmaxf(fmaf(x1, W1[128+c+1], fmaf(x0, W1[c+1], b1[c+1])), 0.f);
    float h0 = fmaf(x1, Ws[128+c],   fmaf(x0, Ws[c],   bs[c]));
    float h1 = fmaf(x1, Ws[128+c+1], fmaf(x0, Ws[c+1], bs[c+1]));
    u2[idx] = pack2(u0, u1);
    h2[idx] = pack2(h0, h1);
}

// ------- bf16 MFMA GEMM v2: B in LDS (per 128-k chunk), A fragments direct from global -------
// K = NK*128, A given as NK chunk base pointers (row stride Astr shorts).
// C bf16 [Nrows x ldC]; BETA: += (Rres ? Rres : C); RELU on output.
// Epilogue: acc -> bf16 staged in LDS (reuse Bs) -> coalesced int4 stores.
template<int NK, int RELU, int BETA>
__global__ __launch_bounds__(256) void gemm2_k(
    const short* __restrict__ A0, const short* __restrict__ A1,
    const short* __restrict__ A2, const short* __restrict__ A3,
    const short* __restrict__ A4, int Astr,
    const short* __restrict__ Wt, int ldWt,
    const float* __restrict__ bias, short* __restrict__ C, const short* __restrict__ Rres,
    int Nrows, int ldC)
{
    __shared__ short Bs[128][136];   // 272B row stride = 17*16B: 16B-aligned, 2-way banks (free)
    const int row0 = blockIdx.x * 128;
    const int col0 = blockIdx.y * 128;
    const int t = threadIdx.x;
    const int w = t >> 6, lane = t & 63, q = lane >> 4, m = lane & 15;

    f32x4 acc[2][8];
    #pragma unroll
    for (int rb = 0; rb < 2; ++rb)
        #pragma unroll
        for (int cb = 0; cb < 8; ++cb)
            acc[rb][cb] = (f32x4){0.f, 0.f, 0.f, 0.f};

    const short* Asrc[5] = {A0, A1, A2, A3, A4};
    int rr0 = row0 + w*32 + m;      if (rr0 > Nrows - 1) rr0 = Nrows - 1;
    int rr1 = row0 + w*32 + 16 + m; if (rr1 > Nrows - 1) rr1 = Nrows - 1;

    #pragma unroll
    for (int kh = 0; kh < NK; ++kh) {
        if (kh) __syncthreads();
        // stage B chunk: 128 cols x 128 k bf16 = 32KB; 8 x int4 per thread, all independent
        #pragma unroll
        for (int it = 0; it < 8; ++it) {
            int ci = t + it * 256;
            int r = ci >> 4, j = (ci & 15) * 8;
            *(int4*)&Bs[r][j] = *(const int4*)(Wt + (size_t)(col0 + r) * ldWt + kh * 128 + j);
        }
        const short* pa0 = Asrc[kh] + (size_t)rr0 * Astr + q * 8;
        const short* pa1 = Asrc[kh] + (size_t)rr1 * Astr + q * 8;
        __syncthreads();
        #pragma unroll
        for (int ks = 0; ks < 4; ++ks) {
            bf16x8 af0 = *(const bf16x8*)(pa0 + ks * 32);
            bf16x8 af1 = *(const bf16x8*)(pa1 + ks * 32);
            bf16x8 bfr[8];
            #pragma unroll
            for (int cb = 0; cb < 8; ++cb)
                bfr[cb] = *(const bf16x8*)&Bs[cb * 16 + m][ks * 32 + q * 8];
            #pragma unroll
            for (int cb = 0; cb < 8; ++cb) {
                acc[0][cb] = __builtin_amdgcn_mfma_f32_16x16x32_bf16(af0, bfr[cb], acc[0][cb], 0, 0, 0);
                acc[1][cb] = __builtin_amdgcn_mfma_f32_16x16x32_bf16(af1, bfr[cb], acc[1][cb], 0, 0, 0);
            }
        }
    }

    // ---- epilogue: stage bf16 tile in LDS, then coalesced 16B global stores ----
    __syncthreads();   // all waves done reading Bs
    #pragma unroll
    for (int rb = 0; rb < 2; ++rb) {
        #pragma unroll
        for (int r = 0; r < 4; ++r) {
            int lrow = w * 32 + rb * 16 + q * 4 + r;
            #pragma unroll
            for (int cb = 0; cb < 8; ++cb) {
                float v = acc[rb][cb][r];
                if (bias) v += bias[col0 + cb * 16 + m];
                if (RELU) v = fmaxf(v, 0.f);
                Bs[lrow][cb * 16 + m] = f2bf(v);
            }
        }
    }
    __syncthreads();
    const short* Rd = Rres ? Rres : C;
    int r2 = t >> 1;
    int cbase = (t & 1) * 64;
    int grow = row0 + r2;
    if (grow < Nrows) {
        size_t gb = (size_t)grow * ldC + col0 + cbase;
        #pragma unroll
        for (int j = 0; j < 8; ++j) {
            int4 cv = *(const int4*)&Bs[r2][cbase + j * 8];
            if (BETA) {
                int4 rv = *(const int4*)(Rd + gb + j * 8);
                int* cp = (int*)&cv; const int* rp = (const int*)&rv;
                #pragma unroll
                for (int e = 0; e < 4; ++e) {
                    float lo = bflo(cp[e]) + bflo(rp[e]);
                    float hi = bfhi(cp[e]) + bfhi(rp[e]);
                    cp[e] = pack2(lo, hi);
                }
            }
            *(int4*)(C + gb + j * 8) = cv;
        }
    }
}

// ---------------- CSR build ----------------
__global__ void count_k(const int* __restrict__ dst, int* __restrict__ cnt, int E) {
    int e = blockIdx.x * 256 + threadIdx.x;
    if (e < E) atomicAdd(&cnt[dst[e]], 1);
}

__global__ __launch_bounds__(256) void scan_part_k(const int* __restrict__ cnt,
                                                   int* __restrict__ bsum, int Nn) {
    __shared__ int red[256];
    int base = blockIdx.x * 1024;
    int s = 0;
    for (int i = threadIdx.x; i < 1024; i += 256) {
        int g = base + i;
        if (g < Nn) s += cnt[g];
    }
    red[threadIdx.x] = s; __syncthreads();
    for (int off = 128; off; off >>= 1) {
        if ((int)threadIdx.x < off) red[threadIdx.x] += red[threadIdx.x + off];
        __syncthreads();
    }
    if (threadIdx.x == 0) bsum[blockIdx.x] = red[0];
}

__global__ __launch_bounds__(256) void scan_top_k(int* __restrict__ bsum, int nb) {
    __shared__ int buf[256];
    int v = ((int)threadIdx.x < nb) ? bsum[threadIdx.x] : 0;
    buf[threadIdx.x] = v; __syncthreads();
    for (int off = 1; off < 256; off <<= 1) {
        int tv = ((int)threadIdx.x >= off) ? buf[threadIdx.x - off] : 0;
        __syncthreads();
        buf[threadIdx.x] += tv;
        __syncthreads();
    }
    if ((int)threadIdx.x < nb) bsum[threadIdx.x] = buf[threadIdx.x] - v;
}

__global__ __launch_bounds__(256) void scan_fin_k(const int* __restrict__ cnt,
    const int* __restrict__ bsum, int* __restrict__ rowptr, int* __restrict__ wpos, int Nn)
{
    __shared__ int tsum[256];
    int base = blockIdx.x * 1024;
    int g0 = base + (int)threadIdx.x * 4;
    int v[4]; int s = 0;
    #pragma unroll
    for (int j = 0; j < 4; ++j) {
        int g = g0 + j;
        v[j] = (g < Nn) ? cnt[g] : 0;
        s += v[j];
    }
    tsum[threadIdx.x] = s; __syncthreads();
    for (int off = 1; off < 256; off <<= 1) {
        int tv = ((int)threadIdx.x >= off) ? tsum[threadIdx.x - off] : 0;
        __syncthreads();
        tsum[threadIdx.x] += tv;
        __syncthreads();
    }
    int run = bsum[blockIdx.x] + tsum[threadIdx.x] - s;
    #pragma unroll
    for (int j = 0; j < 4; ++j) {
        int g = g0 + j;
        if (g < Nn) { wpos[g] = run; rowptr[g + 1] = run + v[j]; }
        run += v[j];
    }
    if (blockIdx.x == 0 && threadIdx.x == 0) rowptr[0] = 0;
}

__global__ void scatter_k(const int* __restrict__ src, const int* __restrict__ dst,
                          int* __restrict__ wpos, int* __restrict__ esrc, int E) {
    int e = blockIdx.x * 256 + threadIdx.x;
    if (e < E) {
        int p = atomicAdd(&wpos[dst[e]], 1);
        esrc[p] = src[e];
    }
}

// ---------------- attention scalars el/er (z bf16) ----------------
__global__ __launch_bounds__(256) void elr_k(const short* __restrict__ z,
    const float* __restrict__ al, const float* __restrict__ ar,
    float* __restrict__ el, float* __restrict__ er, int Nn)
{
    int idx = blockIdx.x * 256 + threadIdx.x;  // n*16 + head
    if (idx >= Nn * 16) return;
    int hd = idx & 15;
    int4 zv = *(const int4*)(z + (size_t)idx * 8);
    float zf[8];
    zf[0] = bflo(zv.x); zf[1] = bfhi(zv.x);
    zf[2] = bflo(zv.y); zf[3] = bfhi(zv.y);
    zf[4] = bflo(zv.z); zf[5] = bfhi(zv.z);
    zf[6] = bflo(zv.w); zf[7] = bfhi(zv.w);
    float sl = 0.f, sr = 0.f;
    #pragma unroll
    for (int j = 0; j < 8; ++j) {
        sl = fmaf(zf[j], al[hd*8 + j], sl);
        sr = fmaf(zf[j], ar[hd*8 + j], sr);
    }
    el[idx] = sl; er[idx] = sr;
}

// ---------------- GAT aggregate: online softmax, one wave per node, unroll x2 ----------------
__global__ __launch_bounds__(256) void gat_k(
    const short* __restrict__ h, const short* __restrict__ z,
    const float* __restrict__ el, const float* __restrict__ er,
    const int* __restrict__ rowptr, const int* __restrict__ esrc,
    const float* __restrict__ gbias, short* __restrict__ t1, int Nn)
{
    int gw = (blockIdx.x * 256 + threadIdx.x) >> 6;
    if (gw >= Nn) return;
    int lane = threadIdx.x & 63;
    int c = lane * 2;
    int head = lane >> 2;
    float ern = er[gw*16 + head];
    int beg = rowptr[gw], end = rowptr[gw+1];
    float m = -3.0e38f, den = 0.f, a0 = 0.f, a1 = 0.f;
    int i = beg;
    for (; i + 1 < end; i += 2) {
        int s0 = esrc[i], s1 = esrc[i+1];
        float e0 = el[s0*16 + head] + ern;
        float e1 = el[s1*16 + head] + ern;
        int zz0 = *(const int*)(z + (size_t)s0*128 + c);
        int zz1 = *(const int*)(z + (size_t)s1*128 + c);
        e0 = (e0 > 0.f) ? e0 : 0.2f * e0;
        e1 = (e1 > 0.f) ? e1 : 0.2f * e1;
        float nm = fmaxf(m, fmaxf(e0, e1));
        float sc = __expf(m - nm);
        float w0 = __expf(e0 - nm);
        float w1 = __expf(e1 - nm);
        den = fmaf(den, sc, w0 + w1);
        a0  = fmaf(a0, sc, fmaf(w0, bflo(zz0), w1 * bflo(zz1)));
        a1  = fmaf(a1, sc, fmaf(w0, bfhi(zz0), w1 * bfhi(zz1)));
        m = nm;
    }
    if (i < end) {
        int s0 = esrc[i];
        float e0 = el[s0*16 + head] + ern;
        int zz0 = *(const int*)(z + (size_t)s0*128 + c);
        e0 = (e0 > 0.f) ? e0 : 0.2f * e0;
        float nm = fmaxf(m, e0);
        float sc = __expf(m - nm);
        float w0 = __expf(e0 - nm);
        den = fmaf(den, sc, w0);
        a0  = fmaf(a0, sc, w0 * bflo(zz0));
        a1  = fmaf(a1, sc, w0 * bfhi(zz0));
    }
    float inv = 1.f / den;
    size_t o = (size_t)gw*64 + lane;
    int hv = ((const int*)h)[o];
    float r0 = bflo(hv) + a0*inv + gbias[c];
    float r1 = bfhi(hv) + a1*inv + gbias[c+1];
    ((int*)t1)[o] = pack2(r0, r1);
}

// ---------------- BatchNorm (bf16 in, fp32 stats) ----------------
__global__ __launch_bounds__(256) void bn_stats_k(const short* __restrict__ xin,
    float* __restrict__ stats, int Nn)
{
    __shared__ float s0s[256], s1s[256], q0s[256], q1s[256];
    int pair = threadIdx.x & 63;
    int slot = threadIdx.x >> 6;
    float s0 = 0.f, s1 = 0.f, q0 = 0.f, q1 = 0.f;
    for (int r = blockIdx.x*4 + slot; r < Nn; r += gridDim.x*4) {
        int v = *(const int*)(xin + (size_t)r*128 + pair*2);
        float a = bflo(v), b = bfhi(v);
        s0 += a; s1 += b;
        q0 = fmaf(a, a, q0); q1 = fmaf(b, b, q1);
    }
    s0s[threadIdx.x] = s0; s1s[threadIdx.x] = s1;
    q0s[threadIdx.x] = q0; q1s[threadIdx.x] = q1;
    __syncthreads();
    if (slot == 0) {
        #pragma unroll
        for (int j = 1; j < 4; ++j) {
            s0 += s0s[pair + j*64]; s1 += s1s[pair + j*64];
            q0 += q0s[pair + j*64]; q1 += q1s[pair + j*64];
        }
        atomicAdd(&stats[pair*2],       s0);
        atomicAdd(&stats[pair*2+1],     s1);
        atomicAdd(&stats[128+pair*2],   q0);
        atomicAdd(&stats[128+pair*2+1], q1);
    }
}

__global__ __launch_bounds__(256) void bn_apply_k(const short* __restrict__ xin,
    const float* __restrict__ stats, const float* __restrict__ g, const float* __restrict__ b,
    short* __restrict__ hout, int Nn)
{
    int idx = blockIdx.x * 256 + threadIdx.x;
    if (idx >= Nn * 64) return;
    int c = (idx & 63) * 2;
    float invN = 1.f / (float)Nn;
    float mu0 = stats[c] * invN,   mu1 = stats[c+1] * invN;
    float v0 = stats[128+c] * invN - mu0*mu0;
    float v1 = stats[128+c+1] * invN - mu1*mu1;
    float sc0 = rsqrtf(v0 + 1e-5f) * g[c],   sc1 = rsqrtf(v1 + 1e-5f) * g[c+1];
    int v = ((const int*)xin)[idx];
    float y0 = (bflo(v) - mu0) * sc0 + b[c];
    float y1 = (bfhi(v) - mu1) * sc1 + b[c+1];
    ((int*)hout)[idx] = pack2(y0, y1);
}

// ---------------- decoder output: out[n] = udec[n,:] . W2 + b2 (udec bf16, relu pre-applied) ----------------
__global__ __launch_bounds__(256) void dec_out_k(const short* __restrict__ udec,
    const float* __restrict__ W2, const float* __restrict__ b2,
    float* __restrict__ out, int Nn)
{
    int gw = (blockIdx.x * 256 + threadIdx.x) >> 6;
    if (gw >= Nn) return;
    int lane = threadIdx.x & 63;
    int v = ((const int*)(udec + (size_t)gw * 128))[lane];
    float p = bflo(v) * W2[lane*2] + bfhi(v) * W2[lane*2 + 1];
    #pragma unroll
    for (int off = 32; off > 0; off >>= 1) p += __shfl_down(p, off);
    if (lane == 0) out[gw] = p + b2[0];
}

extern "C" void kernel_launch(void* const* d_in, const int* in_sizes, int n_in,
                              void* d_out, int out_size, void* d_ws, size_t ws_size,
                              hipStream_t stream)
{
    const float* x      = (const float*)d_in[0];
    const int*   src    = (const int*)  d_in[1];
    const int*   dst    = (const int*)  d_in[2];
    const float* emb_W1 = (const float*)d_in[3];
    const float* emb_b1 = (const float*)d_in[4];
    const float* emb_W2 = (const float*)d_in[5];
    const float* emb_b2 = (const float*)d_in[6];
    const float* emb_Ws = (const float*)d_in[7];
    const float* emb_bs = (const float*)d_in[8];
    const float* gat_W  = (const float*)d_in[9];
    const float* gat_al = (const float*)d_in[10];
    const float* gat_ar = (const float*)d_in[11];
    const float* gat_b  = (const float*)d_in[12];
    const float* bn1_g  = (const float*)d_in[13];
    const float* bn1_b  = (const float*)d_in[14];
    const float* ff_W1  = (const float*)d_in[15];
    const float* ff_b1  = (const float*)d_in[16];
    const float* ff_W2  = (const float*)d_in[17];
    const float* ff_b2  = (const float*)d_in[18];
    const float* bn2_g  = (const float*)d_in[19];
    const float* bn2_b  = (const float*)d_in[20];
    const float* dec_W1 = (const float*)d_in[21];
    const float* dec_b1 = (const float*)d_in[22];
    const float* dec_W2 = (const float*)d_in[23];
    const float* dec_b2 = (const float*)d_in[24];
    float* out = (float*)d_out;
    (void)n_in; (void)out_size;

    const int N = in_sizes[0] / 2;
    const int E = in_sizes[1];

    // ---- workspace (~235 MB) ----
    char* p = (char*)d_ws;
    size_t used = 0;
    auto carve = [&](size_t bytes) {
        char* r = p; size_t a = (bytes + 255) & ~(size_t)255;
        p += a; used += a; return r;
    };
    const size_t nbH = (size_t)N * 128 * 2;   // one bf16 feature map
    short* xs[5];
    for (int i = 0; i < 5; ++i) xs[i] = (short*)carve(nbH);
    short* hmid = (short*)carve(nbH);
    short* t1   = (short*)carve(nbH);
    char*  big  = (char*)carve(2 * nbH);      // u / (z | el | er) / ffh / udec
    int*   cnt    = (int*)carve((size_t)N * 4);
    float* stats8 = (float*)carve(8 * 256 * 4);   // adjacent to cnt: zeroed together
    int*   rowptr = (int*)carve((size_t)(N + 1) * 4);
    int*   wpos   = (int*)carve((size_t)N * 4);
    int*   esrc   = (int*)carve((size_t)E * 4);
    int*   bsum   = (int*)carve(256 * 4);
    short* emb_W2t = (short*)carve((size_t)128 * 128 * 2);
    short* gat_Wt  = (short*)carve((size_t)4 * 128 * 128 * 2);
    short* ff_W1t  = (short*)carve((size_t)4 * 128 * 256 * 2);
    short* ff_W2t  = (short*)carve((size_t)4 * 256 * 128 * 2);
    short* dec_W1t = (short*)carve((size_t)640 * 128 * 2);
    if (used > ws_size) return;

    short* u    = (short*)big;                    // embed phase
    short* z    = (short*)big;                    // GAT phase
    float* el   = (float*)(big + nbH);            // GAT phase
    float* er   = el + (size_t)N * 16;
    short* ffh  = (short*)big;                    // FF phase (N x 256)
    short* udec = (short*)big;                    // decoder phase

    dim3 b256(256);
    int ecb  = (E + 255) / 256;
    int nel2 = (N * 64 + 255) / 256;
    int gx   = (N + 127) / 128;
    int nwv  = (N + 3) / 4;
    int nb   = (N + 1023) / 1024;

    // ---- weight convert + transpose ----
    wconv_k<<<dim3(64, 1), b256, 0, stream>>>(emb_W2, emb_W2t, 128, 128);
    wconv_k<<<dim3(64, 4), b256, 0, stream>>>(gat_W,  gat_Wt,  128, 128);
    wconv_k<<<dim3(128, 4), b256, 0, stream>>>(ff_W1, ff_W1t,  128, 256);
    wconv_k<<<dim3(128, 4), b256, 0, stream>>>(ff_W2, ff_W2t,  256, 128);
    wconv_k<<<dim3(320, 1), b256, 0, stream>>>(dec_W1, dec_W1t, 640, 128);

    // ---- zero cnt + 8 BN stats buffers (contiguous) ----
    {
        int ztot = (int)(((char*)(stats8 + 8*256) - (char*)cnt) / 4);
        zero_i32_k<<<(ztot + 255) / 256, b256, 0, stream>>>(cnt, ztot);
    }

    // ---- CSR build ----
    count_k<<<ecb, b256, 0, stream>>>(dst, cnt, E);
    scan_part_k<<<nb, b256, 0, stream>>>(cnt, bsum, N);
    scan_top_k<<<1, b256, 0, stream>>>(bsum, nb);
    scan_fin_k<<<nb, b256, 0, stream>>>(cnt, bsum, rowptr, wpos, N);
    scatter_k<<<ecb, b256, 0, stream>>>(src, dst, wpos, esrc, E);

    // ---- embed: xs0 = relu(x@W1+b1)@W2 + b2 + (x@Ws+bs) ----
    embed_k<<<nel2, b256, 0, stream>>>(x, emb_W1, emb_b1, emb_Ws, emb_bs, (int*)u, (int*)xs[0], N);
    gemm2_k<1,0,1><<<dim3(gx,1), b256, 0, stream>>>(u,u,u,u,u, 128, emb_W2t, 128,
                                                    emb_b2, xs[0], nullptr, N, 128);

    for (int l = 0; l < 4; ++l) {
        float* st1 = stats8 + (size_t)(l*2)   * 256;
        float* st2 = stats8 + (size_t)(l*2+1) * 256;
        short* hl = xs[l];
        // z = xs[l] @ gatW[l]
        gemm2_k<1,0,0><<<dim3(gx,1), b256, 0, stream>>>(hl,hl,hl,hl,hl, 128,
            gat_Wt + (size_t)l*128*128, 128, nullptr, z, nullptr, N, 128);
        elr_k<<<(N*16 + 255)/256, b256, 0, stream>>>(z, gat_al + l*128, gat_ar + l*128, el, er, N);
        gat_k<<<nwv, b256, 0, stream>>>(hl, z, el, er, rowptr, esrc, gat_b + l*128, t1, N);
        bn_stats_k<<<400, b256, 0, stream>>>(t1, st1, N);
        bn_apply_k<<<nel2, b256, 0, stream>>>(t1, st1, bn1_g + l*128, bn1_b + l*128, hmid, N);
        // FF: ffh = relu(hmid@W1+b1); t1 = hmid + ffh@W2 + b2
        gemm2_k<1,1,0><<<dim3(gx,2), b256, 0, stream>>>(hmid,hmid,hmid,hmid,hmid, 128,
            ff_W1t + (size_t)l*128*256, 128, ff_b1 + l*256, ffh, nullptr, N, 256);
        gemm2_k<2,0,1><<<dim3(gx,1), b256, 0, stream>>>(ffh, ffh + 128, ffh, ffh, ffh, 256,
            ff_W2t + (size_t)l*256*128, 256, ff_b2 + l*128, t1, hmid, N, 128);
        bn_stats_k<<<400, b256, 0, stream>>>(t1, st2, N);
        bn_apply_k<<<nel2, b256, 0, stream>>>(t1, st2, bn2_g + l*128, bn2_b + l*128, xs[l+1], N);
    }

    // ---- decoder: udec = relu(concat(xs) @ dec_W1 + b1)  (virtual concat, K=640) ----
    gemm2_k<5,1,0><<<dim3(gx,1), b256, 0, stream>>>(xs[0], xs[1], xs[2], xs[3], xs[4], 128,
        dec_W1t, 640, dec_b1, udec, nullptr, N, 128);
    dec_out_k<<<nwv, b256, 0, stream>>>(udec, dec_W2, dec_b2, out, N);
}

// Round 8
// 1371.648 us; speedup vs baseline: 2.0213x; 1.0492x over previous
//
#include <hip/hip_runtime.h>
#include <math.h>

typedef __attribute__((ext_vector_type(8))) short bf16x8;
typedef __attribute__((ext_vector_type(4))) float f32x4;

static __device__ __forceinline__ short f2bf(float f) {
    unsigned u = __float_as_uint(f);
    unsigned r = (u + 0x7fffu + ((u >> 16) & 1u)) >> 16;
    return (short)r;
}
static __device__ __forceinline__ float bf2f(short s) {
    return __uint_as_float(((unsigned)(unsigned short)s) << 16);
}
static __device__ __forceinline__ float bflo(int v) { return bf2f((short)(v & 0xffff)); }
static __device__ __forceinline__ float bfhi(int v) { return bf2f((short)(((unsigned)v) >> 16)); }
static __device__ __forceinline__ int pack2(float a, float b) {
    return (int)(((unsigned)(unsigned short)f2bf(b) << 16) | (unsigned)(unsigned short)f2bf(a));
}

// ---------------- zero fill ----------------
__global__ void zero_i32_k(int* __restrict__ p, int n) {
    int i = blockIdx.x * 256 + threadIdx.x;
    if (i < n) p[i] = 0;
}

// ---------------- weight convert+transpose: W[K x Nc] fp32 -> Wt[Nc x K] bf16 ----------------
__global__ __launch_bounds__(256) void wconv_k(const float* __restrict__ W, short* __restrict__ Wt,
                                               int K, int Nc) {
    int slice = blockIdx.y;
    const float* src = W + (size_t)slice * K * Nc;
    short* dst = Wt + (size_t)slice * K * Nc;
    int idx = blockIdx.x * 256 + threadIdx.x;
    if (idx >= K * Nc) return;
    int k = idx / Nc, n = idx - k * Nc;
    dst[(size_t)n * K + k] = f2bf(src[idx]);
}

// ---------------- embed: u = relu(x@W1+b1), h = x@Ws+bs (both bf16) ----------------
__global__ __launch_bounds__(256) void embed_k(
    const float* __restrict__ x, const float* __restrict__ W1, const float* __restrict__ b1,
    const float* __restrict__ Ws, const float* __restrict__ bs,
    int* __restrict__ u2, int* __restrict__ h2, int Nn)
{
    int idx = blockIdx.x * 256 + threadIdx.x;
    if (idx >= Nn * 64) return;
    int n = idx >> 6, c = (idx & 63) * 2;
    float x0 = x[2*n], x1 = x[2*n+1];
    float u0 = fmaxf(fmaf(x1, W1[128+c],   fmaf(x0, W1[c],   b1[c])),   0.f);
    float u1 = fmaxf(fmaf(x1, W1[128+c+1], fmaf(x0, W1[c+1], b1[c+1])), 0.f);
    float h0 = fmaf(x1, Ws[128+c],   fmaf(x0, Ws[c],   bs[c]));
    float h1 = fmaf(x1, Ws[128+c+1], fmaf(x0, Ws[c+1], bs[c+1]));
    u2[idx] = pack2(u0, u1);
    h2[idx] = pack2(h0, h1);
}

// ------- bf16 MFMA GEMM v3: B in LDS, A prefetched to registers BEFORE the barrier -------
// K = NK*128, A given as NK chunk base pointers (row stride Astr shorts).
// C bf16 [Nrows x ldC]; BETA: += (Rres ? Rres : C); RELU on output.
// ELR: also emit el/er = per-head dots of C rows with al/ar (only for z-GEMM: no bias/beta/relu).
template<int NK, int RELU, int BETA, int ELR>
__global__ __launch_bounds__(256) void gemm2_k(
    const short* __restrict__ A0, const short* __restrict__ A1,
    const short* __restrict__ A2, const short* __restrict__ A3,
    const short* __restrict__ A4, int Astr,
    const short* __restrict__ Wt, int ldWt,
    const float* __restrict__ bias, short* __restrict__ C, const short* __restrict__ Rres,
    int Nrows, int ldC,
    const float* __restrict__ al, const float* __restrict__ ar,
    float* __restrict__ elo, float* __restrict__ ero)
{
    __shared__ short Bs[128][136];   // 272B row stride = 17*16B: 16B-aligned, 2-way banks (free)
    const int row0 = blockIdx.x * 128;
    const int col0 = blockIdx.y * 128;
    const int t = threadIdx.x;
    const int w = t >> 6, lane = t & 63, q = lane >> 4, m = lane & 15;

    f32x4 acc[2][8];
    #pragma unroll
    for (int rb = 0; rb < 2; ++rb)
        #pragma unroll
        for (int cb = 0; cb < 8; ++cb)
            acc[rb][cb] = (f32x4){0.f, 0.f, 0.f, 0.f};

    const short* Asrc[5] = {A0, A1, A2, A3, A4};
    int rr0 = row0 + w*32 + m;      if (rr0 > Nrows - 1) rr0 = Nrows - 1;
    int rr1 = row0 + w*32 + 16 + m; if (rr1 > Nrows - 1) rr1 = Nrows - 1;

    #pragma unroll
    for (int kh = 0; kh < NK; ++kh) {
        if (kh) __syncthreads();
        // stage B chunk: 128 cols x 128 k bf16 = 32KB; 8 x int4 per thread, all independent
        #pragma unroll
        for (int it = 0; it < 8; ++it) {
            int ci = t + it * 256;
            int r = ci >> 4, j = (ci & 15) * 8;
            *(int4*)&Bs[r][j] = *(const int4*)(Wt + (size_t)(col0 + r) * ldWt + kh * 128 + j);
        }
        // prefetch ALL A fragments for this chunk into registers (latency overlaps barrier)
        const short* pa0 = Asrc[kh] + (size_t)rr0 * Astr + q * 8;
        const short* pa1 = Asrc[kh] + (size_t)rr1 * Astr + q * 8;
        bf16x8 af0[4], af1[4];
        #pragma unroll
        for (int ks = 0; ks < 4; ++ks) {
            af0[ks] = *(const bf16x8*)(pa0 + ks * 32);
            af1[ks] = *(const bf16x8*)(pa1 + ks * 32);
        }
        __syncthreads();
        #pragma unroll
        for (int ks = 0; ks < 4; ++ks) {
            bf16x8 bfr[8];
            #pragma unroll
            for (int cb = 0; cb < 8; ++cb)
                bfr[cb] = *(const bf16x8*)&Bs[cb * 16 + m][ks * 32 + q * 8];
            #pragma unroll
            for (int cb = 0; cb < 8; ++cb) {
                acc[0][cb] = __builtin_amdgcn_mfma_f32_16x16x32_bf16(af0[ks], bfr[cb], acc[0][cb], 0, 0, 0);
                acc[1][cb] = __builtin_amdgcn_mfma_f32_16x16x32_bf16(af1[ks], bfr[cb], acc[1][cb], 0, 0, 0);
            }
        }
    }

    // ---- epilogue: stage bf16 tile in LDS, then coalesced 16B global stores ----
    __syncthreads();   // all waves done reading Bs
    #pragma unroll
    for (int rb = 0; rb < 2; ++rb) {
        #pragma unroll
        for (int r = 0; r < 4; ++r) {
            int lrow = w * 32 + rb * 16 + q * 4 + r;
            #pragma unroll
            for (int cb = 0; cb < 8; ++cb) {
                float v = acc[rb][cb][r];
                if (bias) v += bias[col0 + cb * 16 + m];
                if (RELU) v = fmaxf(v, 0.f);
                Bs[lrow][cb * 16 + m] = f2bf(v);
            }
        }
    }
    __syncthreads();
    const short* Rd = Rres ? Rres : C;
    int r2 = t >> 1;
    int cbase = (t & 1) * 64;
    int grow = row0 + r2;
    if (grow < Nrows) {
        size_t gb = (size_t)grow * ldC + col0 + cbase;
        float elv[8], erv[8];
        #pragma unroll
        for (int j = 0; j < 8; ++j) {
            int4 cv = *(const int4*)&Bs[r2][cbase + j * 8];
            if (BETA) {
                int4 rv = *(const int4*)(Rd + gb + j * 8);
                int* cp = (int*)&cv; const int* rp = (const int*)&rv;
                #pragma unroll
                for (int e = 0; e < 4; ++e) {
                    float lo = bflo(cp[e]) + bflo(rp[e]);
                    float hi = bfhi(cp[e]) + bfhi(rp[e]);
                    cp[e] = pack2(lo, hi);
                }
            }
            if (ELR) {
                // this int4 is exactly one head (8 channels): head = cbase/8 + j
                const float* alp = al + cbase + j * 8;
                const float* arp = ar + cbase + j * 8;
                const int* cp = (const int*)&cv;
                float sl = 0.f, sr = 0.f;
                #pragma unroll
                for (int e = 0; e < 4; ++e) {
                    float lo = bflo(cp[e]), hi = bfhi(cp[e]);
                    sl = fmaf(lo, alp[2*e], sl); sl = fmaf(hi, alp[2*e+1], sl);
                    sr = fmaf(lo, arp[2*e], sr); sr = fmaf(hi, arp[2*e+1], sr);
                }
                elv[j] = sl; erv[j] = sr;
            }
            *(int4*)(C + gb + j * 8) = cv;
        }
        if (ELR) {
            float* ep = elo + (size_t)grow * 16 + (t & 1) * 8;
            float* rp = ero + (size_t)grow * 16 + (t & 1) * 8;
            *(float4*)ep       = make_float4(elv[0], elv[1], elv[2], elv[3]);
            *(float4*)(ep + 4) = make_float4(elv[4], elv[5], elv[6], elv[7]);
            *(float4*)rp       = make_float4(erv[0], erv[1], erv[2], erv[3]);
            *(float4*)(rp + 4) = make_float4(erv[4], erv[5], erv[6], erv[7]);
        }
    }
}

// ---------------- CSR build ----------------
__global__ void count_k(const int* __restrict__ dst, int* __restrict__ cnt, int E) {
    int e = blockIdx.x * 256 + threadIdx.x;
    if (e < E) atomicAdd(&cnt[dst[e]], 1);
}

__global__ __launch_bounds__(256) void scan_part_k(const int* __restrict__ cnt,
                                                   int* __restrict__ bsum, int Nn) {
    __shared__ int red[256];
    int base = blockIdx.x * 1024;
    int s = 0;
    for (int i = threadIdx.x; i < 1024; i += 256) {
        int g = base + i;
        if (g < Nn) s += cnt[g];
    }
    red[threadIdx.x] = s; __syncthreads();
    for (int off = 128; off; off >>= 1) {
        if ((int)threadIdx.x < off) red[threadIdx.x] += red[threadIdx.x + off];
        __syncthreads();
    }
    if (threadIdx.x == 0) bsum[blockIdx.x] = red[0];
}

__global__ __launch_bounds__(256) void scan_top_k(int* __restrict__ bsum, int nb) {
    __shared__ int buf[256];
    int v = ((int)threadIdx.x < nb) ? bsum[threadIdx.x] : 0;
    buf[threadIdx.x] = v; __syncthreads();
    for (int off = 1; off < 256; off <<= 1) {
        int tv = ((int)threadIdx.x >= off) ? buf[threadIdx.x - off] : 0;
        __syncthreads();
        buf[threadIdx.x] += tv;
        __syncthreads();
    }
    if ((int)threadIdx.x < nb) bsum[threadIdx.x] = buf[threadIdx.x] - v;
}

__global__ __launch_bounds__(256) void scan_fin_k(const int* __restrict__ cnt,
    const int* __restrict__ bsum, int* __restrict__ rowptr, int* __restrict__ wpos, int Nn)
{
    __shared__ int tsum[256];
    int base = blockIdx.x * 1024;
    int g0 = base + (int)threadIdx.x * 4;
    int v[4]; int s = 0;
    #pragma unroll
    for (int j = 0; j < 4; ++j) {
        int g = g0 + j;
        v[j] = (g < Nn) ? cnt[g] : 0;
        s += v[j];
    }
    tsum[threadIdx.x] = s; __syncthreads();
    for (int off = 1; off < 256; off <<= 1) {
        int tv = ((int)threadIdx.x >= off) ? tsum[threadIdx.x - off] : 0;
        __syncthreads();
        tsum[threadIdx.x] += tv;
        __syncthreads();
    }
    int run = bsum[blockIdx.x] + tsum[threadIdx.x] - s;
    #pragma unroll
    for (int j = 0; j < 4; ++j) {
        int g = g0 + j;
        if (g < Nn) { wpos[g] = run; rowptr[g + 1] = run + v[j]; }
        run += v[j];
    }
    if (blockIdx.x == 0 && threadIdx.x == 0) rowptr[0] = 0;
}

__global__ void scatter_k(const int* __restrict__ src, const int* __restrict__ dst,
                          int* __restrict__ wpos, int* __restrict__ esrc, int E) {
    int e = blockIdx.x * 256 + threadIdx.x;
    if (e < E) {
        int p = atomicAdd(&wpos[dst[e]], 1);
        esrc[p] = src[e];
    }
}

// ---------------- GAT aggregate: online softmax, one wave per node, unroll x4 ----------------
__global__ __launch_bounds__(256) void gat_k(
    const short* __restrict__ h, const short* __restrict__ z,
    const float* __restrict__ el, const float* __restrict__ er,
    const int* __restrict__ rowptr, const int* __restrict__ esrc,
    const float* __restrict__ gbias, short* __restrict__ t1, int Nn)
{
    int gw = (blockIdx.x * 256 + threadIdx.x) >> 6;
    if (gw >= Nn) return;
    int lane = threadIdx.x & 63;
    int c = lane * 2;
    int head = lane >> 2;
    float ern = er[gw*16 + head];
    int beg = rowptr[gw], end = rowptr[gw+1];
    float m = -3.0e38f, den = 0.f, a0 = 0.f, a1 = 0.f;
    int i = beg;
    for (; i + 3 < end; i += 4) {
        int s0 = esrc[i], s1 = esrc[i+1], s2 = esrc[i+2], s3 = esrc[i+3];
        float e0 = el[s0*16 + head] + ern;
        float e1 = el[s1*16 + head] + ern;
        float e2 = el[s2*16 + head] + ern;
        float e3 = el[s3*16 + head] + ern;
        int zz0 = *(const int*)(z + (size_t)s0*128 + c);
        int zz1 = *(const int*)(z + (size_t)s1*128 + c);
        int zz2 = *(const int*)(z + (size_t)s2*128 + c);
        int zz3 = *(const int*)(z + (size_t)s3*128 + c);
        e0 = (e0 > 0.f) ? e0 : 0.2f * e0;
        e1 = (e1 > 0.f) ? e1 : 0.2f * e1;
        e2 = (e2 > 0.f) ? e2 : 0.2f * e2;
        e3 = (e3 > 0.f) ? e3 : 0.2f * e3;
        float nm = fmaxf(fmaxf(fmaxf(e0, e1), fmaxf(e2, e3)), m);
        float sc = __expf(m - nm);
        float w0 = __expf(e0 - nm), w1 = __expf(e1 - nm);
        float w2 = __expf(e2 - nm), w3 = __expf(e3 - nm);
        den = fmaf(den, sc, (w0 + w1) + (w2 + w3));
        a0 = fmaf(a0, sc, fmaf(w0, bflo(zz0), fmaf(w1, bflo(zz1), fmaf(w2, bflo(zz2), w3 * bflo(zz3)))));
        a1 = fmaf(a1, sc, fmaf(w0, bfhi(zz0), fmaf(w1, bfhi(zz1), fmaf(w2, bfhi(zz2), w3 * bfhi(zz3)))));
        m = nm;
    }
    for (; i + 1 < end; i += 2) {
        int s0 = esrc[i], s1 = esrc[i+1];
        float e0 = el[s0*16 + head] + ern;
        float e1 = el[s1*16 + head] + ern;
        int zz0 = *(const int*)(z + (size_t)s0*128 + c);
        int zz1 = *(const int*)(z + (size_t)s1*128 + c);
        e0 = (e0 > 0.f) ? e0 : 0.2f * e0;
        e1 = (e1 > 0.f) ? e1 : 0.2f * e1;
        float nm = fmaxf(m, fmaxf(e0, e1));
        float sc = __expf(m - nm);
        float w0 = __expf(e0 - nm);
        float w1 = __expf(e1 - nm);
        den = fmaf(den, sc, w0 + w1);
        a0  = fmaf(a0, sc, fmaf(w0, bflo(zz0), w1 * bflo(zz1)));
        a1  = fmaf(a1, sc, fmaf(w0, bfhi(zz0), w1 * bfhi(zz1)));
        m = nm;
    }
    if (i < end) {
        int s0 = esrc[i];
        float e0 = el[s0*16 + head] + ern;
        int zz0 = *(const int*)(z + (size_t)s0*128 + c);
        e0 = (e0 > 0.f) ? e0 : 0.2f * e0;
        float nm = fmaxf(m, e0);
        float sc = __expf(m - nm);
        float w0 = __expf(e0 - nm);
        den = fmaf(den, sc, w0);
        a0  = fmaf(a0, sc, w0 * bflo(zz0));
        a1  = fmaf(a1, sc, w0 * bfhi(zz0));
    }
    float inv = 1.f / den;
    size_t o = (size_t)gw*64 + lane;
    int hv = ((const int*)h)[o];
    float r0 = bflo(hv) + a0*inv + gbias[c];
    float r1 = bfhi(hv) + a1*inv + gbias[c+1];
    ((int*)t1)[o] = pack2(r0, r1);
}

// ---------------- BatchNorm (bf16 in, fp32 stats) ----------------
__global__ __launch_bounds__(256) void bn_stats_k(const short* __restrict__ xin,
    float* __restrict__ stats, int Nn)
{
    __shared__ float s0s[256], s1s[256], q0s[256], q1s[256];
    int pair = threadIdx.x & 63;
    int slot = threadIdx.x >> 6;
    float s0 = 0.f, s1 = 0.f, q0 = 0.f, q1 = 0.f;
    for (int r = blockIdx.x*4 + slot; r < Nn; r += gridDim.x*4) {
        int v = *(const int*)(xin + (size_t)r*128 + pair*2);
        float a = bflo(v), b = bfhi(v);
        s0 += a; s1 += b;
        q0 = fmaf(a, a, q0); q1 = fmaf(b, b, q1);
    }
    s0s[threadIdx.x] = s0; s1s[threadIdx.x] = s1;
    q0s[threadIdx.x] = q0; q1s[threadIdx.x] = q1;
    __syncthreads();
    if (slot == 0) {
        #pragma unroll
        for (int j = 1; j < 4; ++j) {
            s0 += s0s[pair + j*64]; s1 += s1s[pair + j*64];
            q0 += q0s[pair + j*64]; q1 += q1s[pair + j*64];
        }
        atomicAdd(&stats[pair*2],       s0);
        atomicAdd(&stats[pair*2+1],     s1);
        atomicAdd(&stats[128+pair*2],   q0);
        atomicAdd(&stats[128+pair*2+1], q1);
    }
}

__global__ __launch_bounds__(256) void bn_apply_k(const short* __restrict__ xin,
    const float* __restrict__ stats, const float* __restrict__ g, const float* __restrict__ b,
    short* __restrict__ hout, int Nn)
{
    int idx = blockIdx.x * 256 + threadIdx.x;
    if (idx >= Nn * 64) return;
    int c = (idx & 63) * 2;
    float invN = 1.f / (float)Nn;
    float mu0 = stats[c] * invN,   mu1 = stats[c+1] * invN;
    float v0 = stats[128+c] * invN - mu0*mu0;
    float v1 = stats[128+c+1] * invN - mu1*mu1;
    float sc0 = rsqrtf(v0 + 1e-5f) * g[c],   sc1 = rsqrtf(v1 + 1e-5f) * g[c+1];
    int v = ((const int*)xin)[idx];
    float y0 = (bflo(v) - mu0) * sc0 + b[c];
    float y1 = (bfhi(v) - mu1) * sc1 + b[c+1];
    ((int*)hout)[idx] = pack2(y0, y1);
}

// ---------------- decoder output: out[n] = udec[n,:] . W2 + b2 (udec bf16, relu pre-applied) ----------------
__global__ __launch_bounds__(256) void dec_out_k(const short* __restrict__ udec,
    const float* __restrict__ W2, const float* __restrict__ b2,
    float* __restrict__ out, int Nn)
{
    int gw = (blockIdx.x * 256 + threadIdx.x) >> 6;
    if (gw >= Nn) return;
    int lane = threadIdx.x & 63;
    int v = ((const int*)(udec + (size_t)gw * 128))[lane];
    float p = bflo(v) * W2[lane*2] + bfhi(v) * W2[lane*2 + 1];
    #pragma unroll
    for (int off = 32; off > 0; off >>= 1) p += __shfl_down(p, off);
    if (lane == 0) out[gw] = p + b2[0];
}

extern "C" void kernel_launch(void* const* d_in, const int* in_sizes, int n_in,
                              void* d_out, int out_size, void* d_ws, size_t ws_size,
                              hipStream_t stream)
{
    const float* x      = (const float*)d_in[0];
    const int*   src    = (const int*)  d_in[1];
    const int*   dst    = (const int*)  d_in[2];
    const float* emb_W1 = (const float*)d_in[3];
    const float* emb_b1 = (const float*)d_in[4];
    const float* emb_W2 = (const float*)d_in[5];
    const float* emb_b2 = (const float*)d_in[6];
    const float* emb_Ws = (const float*)d_in[7];
    const float* emb_bs = (const float*)d_in[8];
    const float* gat_W  = (const float*)d_in[9];
    const float* gat_al = (const float*)d_in[10];
    const float* gat_ar = (const float*)d_in[11];
    const float* gat_b  = (const float*)d_in[12];
    const float* bn1_g  = (const float*)d_in[13];
    const float* bn1_b  = (const float*)d_in[14];
    const float* ff_W1  = (const float*)d_in[15];
    const float* ff_b1  = (const float*)d_in[16];
    const float* ff_W2  = (const float*)d_in[17];
    const float* ff_b2  = (const float*)d_in[18];
    const float* bn2_g  = (const float*)d_in[19];
    const float* bn2_b  = (const float*)d_in[20];
    const float* dec_W1 = (const float*)d_in[21];
    const float* dec_b1 = (const float*)d_in[22];
    const float* dec_W2 = (const float*)d_in[23];
    const float* dec_b2 = (const float*)d_in[24];
    float* out = (float*)d_out;
    (void)n_in; (void)out_size;

    const int N = in_sizes[0] / 2;
    const int E = in_sizes[1];

    // ---- workspace (~235 MB) ----
    char* p = (char*)d_ws;
    size_t used = 0;
    auto carve = [&](size_t bytes) {
        char* r = p; size_t a = (bytes + 255) & ~(size_t)255;
        p += a; used += a; return r;
    };
    const size_t nbH = (size_t)N * 128 * 2;   // one bf16 feature map
    short* xs[5];
    for (int i = 0; i < 5; ++i) xs[i] = (short*)carve(nbH);
    short* hmid = (short*)carve(nbH);
    short* t1   = (short*)carve(nbH);
    char*  big  = (char*)carve(2 * nbH);      // u / (z | el | er) / ffh / udec
    int*   cnt    = (int*)carve((size_t)N * 4);
    float* stats8 = (float*)carve(8 * 256 * 4);   // adjacent to cnt: zeroed together
    int*   rowptr = (int*)carve((size_t)(N + 1) * 4);
    int*   wpos   = (int*)carve((size_t)N * 4);
    int*   esrc   = (int*)carve((size_t)E * 4);
    int*   bsum   = (int*)carve(256 * 4);
    short* emb_W2t = (short*)carve((size_t)128 * 128 * 2);
    short* gat_Wt  = (short*)carve((size_t)4 * 128 * 128 * 2);
    short* ff_W1t  = (short*)carve((size_t)4 * 128 * 256 * 2);
    short* ff_W2t  = (short*)carve((size_t)4 * 256 * 128 * 2);
    short* dec_W1t = (short*)carve((size_t)640 * 128 * 2);
    if (used > ws_size) return;

    short* u    = (short*)big;                    // embed phase
    short* z    = (short*)big;                    // GAT phase
    float* el   = (float*)(big + nbH);            // GAT phase
    float* er   = el + (size_t)N * 16;
    short* ffh  = (short*)big;                    // FF phase (N x 256)
    short* udec = (short*)big;                    // decoder phase

    dim3 b256(256);
    int ecb  = (E + 255) / 256;
    int nel2 = (N * 64 + 255) / 256;
    int gx   = (N + 127) / 128;
    int nwv  = (N + 3) / 4;
    int nb   = (N + 1023) / 1024;

    // ---- weight convert + transpose ----
    wconv_k<<<dim3(64, 1), b256, 0, stream>>>(emb_W2, emb_W2t, 128, 128);
    wconv_k<<<dim3(64, 4), b256, 0, stream>>>(gat_W,  gat_Wt,  128, 128);
    wconv_k<<<dim3(128, 4), b256, 0, stream>>>(ff_W1, ff_W1t,  128, 256);
    wconv_k<<<dim3(128, 4), b256, 0, stream>>>(ff_W2, ff_W2t,  256, 128);
    wconv_k<<<dim3(320, 1), b256, 0, stream>>>(dec_W1, dec_W1t, 640, 128);

    // ---- zero cnt + 8 BN stats buffers (contiguous) ----
    {
        int ztot = (int)(((char*)(stats8 + 8*256) - (char*)cnt) / 4);
        zero_i32_k<<<(ztot + 255) / 256, b256, 0, stream>>>(cnt, ztot);
    }

    // ---- CSR build ----
    count_k<<<ecb, b256, 0, stream>>>(dst, cnt, E);
    scan_part_k<<<nb, b256, 0, stream>>>(cnt, bsum, N);
    scan_top_k<<<1, b256, 0, stream>>>(bsum, nb);
    scan_fin_k<<<nb, b256, 0, stream>>>(cnt, bsum, rowptr, wpos, N);
    scatter_k<<<ecb, b256, 0, stream>>>(src, dst, wpos, esrc, E);

    // ---- embed: xs0 = relu(x@W1+b1)@W2 + b2 + (x@Ws+bs) ----
    embed_k<<<nel2, b256, 0, stream>>>(x, emb_W1, emb_b1, emb_Ws, emb_bs, (int*)u, (int*)xs[0], N);
    gemm2_k<1,0,1,0><<<dim3(gx,1), b256, 0, stream>>>(u,u,u,u,u, 128, emb_W2t, 128,
        emb_b2, xs[0], nullptr, N, 128, nullptr, nullptr, nullptr, nullptr);

    for (int l = 0; l < 4; ++l) {
        float* st1 = stats8 + (size_t)(l*2)   * 256;
        float* st2 = stats8 + (size_t)(l*2+1) * 256;
        short* hl = xs[l];
        // z = xs[l] @ gatW[l]  (+ fused el/er)
        gemm2_k<1,0,0,1><<<dim3(gx,1), b256, 0, stream>>>(hl,hl,hl,hl,hl, 128,
            gat_Wt + (size_t)l*128*128, 128, nullptr, z, nullptr, N, 128,
            gat_al + l*128, gat_ar + l*128, el, er);
        gat_k<<<nwv, b256, 0, stream>>>(hl, z, el, er, rowptr, esrc, gat_b + l*128, t1, N);
        bn_stats_k<<<400, b256, 0, stream>>>(t1, st1, N);
        bn_apply_k<<<nel2, b256, 0, stream>>>(t1, st1, bn1_g + l*128, bn1_b + l*128, hmid, N);
        // FF: ffh = relu(hmid@W1+b1); t1 = hmid + ffh@W2 + b2
        gemm2_k<1,1,0,0><<<dim3(gx,2), b256, 0, stream>>>(hmid,hmid,hmid,hmid,hmid, 128,
            ff_W1t + (size_t)l*128*256, 128, ff_b1 + l*256, ffh, nullptr, N, 256,
            nullptr, nullptr, nullptr, nullptr);
        gemm2_k<2,0,1,0><<<dim3(gx,1), b256, 0, stream>>>(ffh, ffh + 128, ffh, ffh, ffh, 256,
            ff_W2t + (size_t)l*256*128, 256, ff_b2 + l*128, t1, hmid, N, 128,
            nullptr, nullptr, nullptr, nullptr);
        bn_stats_k<<<400, b256, 0, stream>>>(t1, st2, N);
        bn_apply_k<<<nel2, b256, 0, stream>>>(t1, st2, bn2_g + l*128, bn2_b + l*128, xs[l+1], N);
    }

    // ---- decoder: udec = relu(concat(xs) @ dec_W1 + b1)  (virtual concat, K=640) ----
    gemm2_k<5,1,0,0><<<dim3(gx,1), b256, 0, stream>>>(xs[0], xs[1], xs[2], xs[3], xs[4], 128,
        dec_W1t, 640, dec_b1, udec, nullptr, N, 128,
        nullptr, nullptr, nullptr, nullptr);
    dec_out_k<<<nwv, b256, 0, stream>>>(udec, dec_W2, dec_b2, out, N);
}